// Round 5
// baseline (819.745 us; speedup 1.0000x reference)
//
#include <hip/hip_runtime.h>
#include <hip/hip_bf16.h>
#include <math.h>

#define ST_E 68
#define ST_W 68
#define ST_WX 132

// pk row layout (bf16 elements): [e0|e1|y2|xt|e2], stride 320
#define SLOT_E0 0
#define SLOT_E1 64
#define SLOT_Y2 128
#define SLOT_XT 192
#define SLOT_E2 256
#define PK_STRIDE 320

__device__ __forceinline__ float4 f4z() { return make_float4(0.f, 0.f, 0.f, 0.f); }
__device__ __forceinline__ void fma4(float4& a, float s, const float4& v) {
  a.x = fmaf(s, v.x, a.x); a.y = fmaf(s, v.y, a.y);
  a.z = fmaf(s, v.z, a.z); a.w = fmaf(s, v.w, a.w);
}
__device__ __forceinline__ float4 add4(const float4& a, const float4& b) {
  return make_float4(a.x + b.x, a.y + b.y, a.z + b.z, a.w + b.w);
}
__device__ __forceinline__ float4 cvt4(const ushort4& u) {
  float4 f;
  f.x = __uint_as_float((unsigned)u.x << 16);
  f.y = __uint_as_float((unsigned)u.y << 16);
  f.z = __uint_as_float((unsigned)u.z << 16);
  f.w = __uint_as_float((unsigned)u.w << 16);
  return f;
}
__device__ __forceinline__ float4 ldbf4(const unsigned short* p) {
  return cvt4(*(const ushort4*)p);
}
__device__ __forceinline__ unsigned short f2bf(float v) {
  __hip_bfloat16 h = __float2bfloat16(v);
  return *reinterpret_cast<unsigned short*>(&h);
}
__device__ __forceinline__ void st4bf(unsigned short* p, const float4& v) {
  ushort4 u;
  u.x = f2bf(v.x); u.y = f2bf(v.y); u.z = f2bf(v.z); u.w = f2bf(v.w);
  *(ushort4*)p = u;
}
__device__ __forceinline__ float fsig(float x) {    // sigmoid, fast
  return __builtin_amdgcn_rcpf(1.f + __expf(-x));
}

// -------- init: pk0 e0/e1/e2 slots = bf16(emb0) --------
__global__ void init_k(const float* __restrict__ emb0, unsigned short* __restrict__ pk0,
                       int N) {
  int idx = blockIdx.x * blockDim.x + threadIdx.x;
  int n = idx >> 4, q = idx & 15;
  if (n >= N) return;
  float4 v = *(const float4*)(emb0 + (size_t)n * 64 + q * 4);
  unsigned short* r = pk0 + (size_t)n * PK_STRIDE + q * 4;
  st4bf(r + SLOT_E0, v);
  st4bf(r + SLOT_E1, v);
  st4bf(r + SLOT_E2, v);
}

// ---------------- CSR build ----------------
__global__ void hist_k(const int* __restrict__ h, int* __restrict__ deg, int E) {
  int i = blockIdx.x * blockDim.x + threadIdx.x;
  if (i < E) atomicAdd(&deg[h[i]], 1);
}

__global__ void scanA_k(const int* __restrict__ deg, int* __restrict__ rp,
                        int* __restrict__ sums, int N) {
  __shared__ int s[1024];
  int i = blockIdx.x * 1024 + threadIdx.x;
  int v = (i < N) ? deg[i] : 0;
  s[threadIdx.x] = v;
  __syncthreads();
  for (int off = 1; off < 1024; off <<= 1) {
    int t = (threadIdx.x >= (unsigned)off) ? s[threadIdx.x - off] : 0;
    __syncthreads();
    s[threadIdx.x] += t;
    __syncthreads();
  }
  if (i < N) rp[i] = s[threadIdx.x] - v;
  if (threadIdx.x == 1023) sums[blockIdx.x] = s[1023];
}

// one-wave exclusive scan over nch chunk sums
__global__ void scanB_k(int* sums, int nch) {
  int lane = threadIdx.x;   // 64 threads
  int run = 0;
  for (int base = 0; base < nch; base += 64) {
    int v = (base + lane < nch) ? sums[base + lane] : 0;
    int incl = v;
    for (int off = 1; off < 64; off <<= 1) {
      int t = __shfl_up(incl, off, 64);
      if (lane >= off) incl += t;
    }
    if (base + lane < nch) sums[base + lane] = run + (incl - v);
    run += __shfl(incl, 63, 64);
  }
}

__global__ void scanC_k(int* __restrict__ rp, int* __restrict__ cur,
                        const int* __restrict__ sums, int N, int E) {
  int i = blockIdx.x * blockDim.x + threadIdx.x;
  if (i < N) {
    int v = rp[i] + sums[i >> 10];
    rp[i] = v; cur[i] = v;
  } else if (i == N) {
    rp[N] = E;
  }
}

__global__ void fill_k(const int* __restrict__ h, int* __restrict__ cur,
                       int* __restrict__ perm, int E) {
  int i = blockIdx.x * blockDim.x + threadIdx.x;
  if (i < E) {
    int pos = atomicAdd(&cur[h[i]], 1);
    perm[pos] = i;
  }
}

// ------- degree-balanced row order: counting sort by degree, descending -------
__device__ __forceinline__ int degbin(int d) { return 63 - min(d, 63); }

__global__ void dhist_k(const int* __restrict__ deg, int* __restrict__ bins, int N) {
  __shared__ int h[64];
  if (threadIdx.x < 64) h[threadIdx.x] = 0;
  __syncthreads();
  int i = blockIdx.x * blockDim.x + threadIdx.x;
  if (i < N) atomicAdd(&h[degbin(deg[i])], 1);
  __syncthreads();
  if (threadIdx.x < 64 && h[threadIdx.x]) atomicAdd(&bins[threadIdx.x], h[threadIdx.x]);
}

__global__ void dscan_k(const int* __restrict__ bins, int* __restrict__ cur2) {
  int lane = threadIdx.x;  // 64
  int v = bins[lane];
  int incl = v;
  for (int off = 1; off < 64; off <<= 1) {
    int t = __shfl_up(incl, off, 64);
    if (lane >= off) incl += t;
  }
  cur2[lane] = incl - v;
}

__global__ void dscatter_k(const int* __restrict__ deg, int* __restrict__ cur2,
                           int* __restrict__ rorder, int N) {
  int i = blockIdx.x * blockDim.x + threadIdx.x;
  if (i < N) {
    int pos = atomicAdd(&cur2[degbin(deg[i])], 1);
    rorder[pos] = i;
  }
}

// ------- pre-gather edge data into CSR slot order; t pre-scaled by PK_STRIDE -------
__global__ void pregather_k(const int* __restrict__ perm, const int* __restrict__ t_idx,
                            const float* __restrict__ G, const float* __restrict__ gum,
                            int2* __restrict__ ep, float* __restrict__ cgum,
                            int E, int L) {
  int j = blockIdx.x * blockDim.x + threadIdx.x;
  if (j < E) {
    int pe = perm[j];
    ep[j] = make_int2(t_idx[pe] * PK_STRIDE, __float_as_int(G[pe]));
    for (int l = 0; l < L; l++) cgum[(size_t)l * E + j] = gum[(size_t)l * E + pe];
  }
}

// ------- xht: xhb[N][64] bf16, xt -> pk XT slot (reads e1 from pk) -------
__global__ __launch_bounds__(256) void xht_k(const unsigned short* __restrict__ pkin,
                                             const float* __restrict__ W,  // [128][64]
                                             unsigned short* __restrict__ xhb,
                                             unsigned short* __restrict__ pk, int N) {
  __shared__ float et[64 * ST_E];
  __shared__ float wl[64 * ST_WX];
  int tid = threadIdx.x;
  int n0 = blockIdx.x * 64;
  for (int i = tid; i < 64 * 16; i += 256) {
    int r = i >> 4, c4 = (i & 15) * 4;
    float4 v = (n0 + r < N)
        ? ldbf4(pkin + (size_t)(n0 + r) * PK_STRIDE + SLOT_E1 + c4) : f4z();
    *(float4*)(et + r * ST_E + c4) = v;
  }
  for (int i = tid; i < 128 * 16; i += 256) {
    int r = i >> 4, c4 = (i & 15) * 4;
    float4 v = *(const float4*)(W + r * 64 + c4);
    if (r < 64) *(float4*)(wl + r * ST_WX + c4) = v;
    else        *(float4*)(wl + (r - 64) * ST_WX + 64 + c4) = v;
  }
  __syncthreads();
  int rg = tid >> 4, tx = tid & 15;
  int s2 = (tx >> 2) * 2;
  float acc[4][8];
#pragma unroll
  for (int i = 0; i < 4; i++)
#pragma unroll
    for (int j = 0; j < 8; j++) acc[i][j] = 0.f;
#pragma unroll 4
  for (int k = 0; k < 64; k++) {
    int kk = (k + s2) & 63;
    float a0 = et[(rg * 4 + 0) * ST_E + kk];
    float a1 = et[(rg * 4 + 1) * ST_E + kk];
    float a2 = et[(rg * 4 + 2) * ST_E + kk];
    float a3 = et[(rg * 4 + 3) * ST_E + kk];
    float4 b0 = *(const float4*)(wl + kk * ST_WX + tx * 8);
    float4 b1 = *(const float4*)(wl + kk * ST_WX + tx * 8 + 4);
    acc[0][0] = fmaf(a0, b0.x, acc[0][0]); acc[0][1] = fmaf(a0, b0.y, acc[0][1]);
    acc[0][2] = fmaf(a0, b0.z, acc[0][2]); acc[0][3] = fmaf(a0, b0.w, acc[0][3]);
    acc[0][4] = fmaf(a0, b1.x, acc[0][4]); acc[0][5] = fmaf(a0, b1.y, acc[0][5]);
    acc[0][6] = fmaf(a0, b1.z, acc[0][6]); acc[0][7] = fmaf(a0, b1.w, acc[0][7]);
    acc[1][0] = fmaf(a1, b0.x, acc[1][0]); acc[1][1] = fmaf(a1, b0.y, acc[1][1]);
    acc[1][2] = fmaf(a1, b0.z, acc[1][2]); acc[1][3] = fmaf(a1, b0.w, acc[1][3]);
    acc[1][4] = fmaf(a1, b1.x, acc[1][4]); acc[1][5] = fmaf(a1, b1.y, acc[1][5]);
    acc[1][6] = fmaf(a1, b1.z, acc[1][6]); acc[1][7] = fmaf(a1, b1.w, acc[1][7]);
    acc[2][0] = fmaf(a2, b0.x, acc[2][0]); acc[2][1] = fmaf(a2, b0.y, acc[2][1]);
    acc[2][2] = fmaf(a2, b0.z, acc[2][2]); acc[2][3] = fmaf(a2, b0.w, acc[2][3]);
    acc[2][4] = fmaf(a2, b1.x, acc[2][4]); acc[2][5] = fmaf(a2, b1.y, acc[2][5]);
    acc[2][6] = fmaf(a2, b1.z, acc[2][6]); acc[2][7] = fmaf(a2, b1.w, acc[2][7]);
    acc[3][0] = fmaf(a3, b0.x, acc[3][0]); acc[3][1] = fmaf(a3, b0.y, acc[3][1]);
    acc[3][2] = fmaf(a3, b0.z, acc[3][2]); acc[3][3] = fmaf(a3, b0.w, acc[3][3]);
    acc[3][4] = fmaf(a3, b1.x, acc[3][4]); acc[3][5] = fmaf(a3, b1.y, acc[3][5]);
    acc[3][6] = fmaf(a3, b1.z, acc[3][6]); acc[3][7] = fmaf(a3, b1.w, acc[3][7]);
  }
#pragma unroll
  for (int i = 0; i < 4; i++) {
    int n = n0 + rg * 4 + i;
    if (n < N) {
      if (tx < 8) {
        unsigned short* xp = xhb + (size_t)n * 64 + tx * 8;
        st4bf(xp, make_float4(acc[i][0], acc[i][1], acc[i][2], acc[i][3]));
        st4bf(xp + 4, make_float4(acc[i][4], acc[i][5], acc[i][6], acc[i][7]));
      } else {
        unsigned short* pp = pk + (size_t)n * PK_STRIDE + SLOT_XT + (tx - 8) * 8;
        st4bf(pp, make_float4(acc[i][0], acc[i][1], acc[i][2], acc[i][3]));
        st4bf(pp + 4, make_float4(acc[i][4], acc[i][5], acc[i][6], acc[i][7]));
      }
    }
  }
}

// ------- node MLP + gate: pk Y2 slot = bf16(sigmoid(gum+mlp(e2))*e2) -------
__global__ __launch_bounds__(256) void mlp2_k(const unsigned short* __restrict__ pkin,
    const float* __restrict__ W1, const float* __restrict__ b1,
    const float* __restrict__ W2, const float* __restrict__ b2,
    const float* __restrict__ gum, unsigned short* __restrict__ pk, int N) {
  __shared__ float et[64 * ST_E];
  __shared__ float w1l[64 * ST_W];
  __shared__ float w2l[64 * ST_W];
  __shared__ float ht[64 * ST_E];
  int tid = threadIdx.x;
  int n0 = blockIdx.x * 64;
  for (int i = tid; i < 64 * 16; i += 256) {
    int r = i >> 4, c4 = (i & 15) * 4;
    float4 v = (n0 + r < N)
        ? ldbf4(pkin + (size_t)(n0 + r) * PK_STRIDE + SLOT_E2 + c4) : f4z();
    *(float4*)(et + r * ST_E + c4) = v;
    *(float4*)(w1l + r * ST_W + c4) = *(const float4*)(W1 + r * 64 + c4);
    *(float4*)(w2l + r * ST_W + c4) = *(const float4*)(W2 + r * 64 + c4);
  }
  __syncthreads();
  int rg = tid >> 4, tx = tid & 15;
  int s2 = (tx >> 2) * 2;
  float acc[4][4];
#pragma unroll
  for (int i = 0; i < 4; i++)
#pragma unroll
    for (int j = 0; j < 4; j++) acc[i][j] = 0.f;
#pragma unroll 4
  for (int k = 0; k < 64; k++) {
    int kk = (k + s2) & 63;
    float a0 = et[(rg * 4 + 0) * ST_E + kk];
    float a1 = et[(rg * 4 + 1) * ST_E + kk];
    float a2 = et[(rg * 4 + 2) * ST_E + kk];
    float a3 = et[(rg * 4 + 3) * ST_E + kk];
    float4 bv = *(const float4*)(w1l + kk * ST_W + tx * 4);
    acc[0][0] = fmaf(a0, bv.x, acc[0][0]); acc[0][1] = fmaf(a0, bv.y, acc[0][1]);
    acc[0][2] = fmaf(a0, bv.z, acc[0][2]); acc[0][3] = fmaf(a0, bv.w, acc[0][3]);
    acc[1][0] = fmaf(a1, bv.x, acc[1][0]); acc[1][1] = fmaf(a1, bv.y, acc[1][1]);
    acc[1][2] = fmaf(a1, bv.z, acc[1][2]); acc[1][3] = fmaf(a1, bv.w, acc[1][3]);
    acc[2][0] = fmaf(a2, bv.x, acc[2][0]); acc[2][1] = fmaf(a2, bv.y, acc[2][1]);
    acc[2][2] = fmaf(a2, bv.z, acc[2][2]); acc[2][3] = fmaf(a2, bv.w, acc[2][3]);
    acc[3][0] = fmaf(a3, bv.x, acc[3][0]); acc[3][1] = fmaf(a3, bv.y, acc[3][1]);
    acc[3][2] = fmaf(a3, bv.z, acc[3][2]); acc[3][3] = fmaf(a3, bv.w, acc[3][3]);
  }
  float4 b1v = *(const float4*)(b1 + tx * 4);
#pragma unroll
  for (int i = 0; i < 4; i++) {
    float4 hv = make_float4(fmaxf(acc[i][0] + b1v.x, 0.f), fmaxf(acc[i][1] + b1v.y, 0.f),
                            fmaxf(acc[i][2] + b1v.z, 0.f), fmaxf(acc[i][3] + b1v.w, 0.f));
    *(float4*)(ht + (rg * 4 + i) * ST_E + tx * 4) = hv;
  }
  __syncthreads();
  float acc2[4][4];
#pragma unroll
  for (int i = 0; i < 4; i++)
#pragma unroll
    for (int j = 0; j < 4; j++) acc2[i][j] = 0.f;
#pragma unroll 4
  for (int k = 0; k < 64; k++) {
    int kk = (k + s2) & 63;
    float a0 = ht[(rg * 4 + 0) * ST_E + kk];
    float a1 = ht[(rg * 4 + 1) * ST_E + kk];
    float a2 = ht[(rg * 4 + 2) * ST_E + kk];
    float a3 = ht[(rg * 4 + 3) * ST_E + kk];
    float4 bv = *(const float4*)(w2l + kk * ST_W + tx * 4);
    acc2[0][0] = fmaf(a0, bv.x, acc2[0][0]); acc2[0][1] = fmaf(a0, bv.y, acc2[0][1]);
    acc2[0][2] = fmaf(a0, bv.z, acc2[0][2]); acc2[0][3] = fmaf(a0, bv.w, acc2[0][3]);
    acc2[1][0] = fmaf(a1, bv.x, acc2[1][0]); acc2[1][1] = fmaf(a1, bv.y, acc2[1][1]);
    acc2[1][2] = fmaf(a1, bv.z, acc2[1][2]); acc2[1][3] = fmaf(a1, bv.w, acc2[1][3]);
    acc2[2][0] = fmaf(a2, bv.x, acc2[2][0]); acc2[2][1] = fmaf(a2, bv.y, acc2[2][1]);
    acc2[2][2] = fmaf(a2, bv.z, acc2[2][2]); acc2[2][3] = fmaf(a2, bv.w, acc2[2][3]);
    acc2[3][0] = fmaf(a3, bv.x, acc2[3][0]); acc2[3][1] = fmaf(a3, bv.y, acc2[3][1]);
    acc2[3][2] = fmaf(a3, bv.z, acc2[3][2]); acc2[3][3] = fmaf(a3, bv.w, acc2[3][3]);
  }
  float4 b2v = *(const float4*)(b2 + tx * 4);
#pragma unroll
  for (int i = 0; i < 4; i++) {
    int n = n0 + rg * 4 + i;
    if (n < N) {
      float4 gv = *(const float4*)(gum + (size_t)n * 64 + tx * 4);
      float4 ev = *(const float4*)(et + (rg * 4 + i) * ST_E + tx * 4);
      float4 yv;
      yv.x = ev.x * fsig(gv.x + acc2[i][0] + b2v.x);
      yv.y = ev.y * fsig(gv.y + acc2[i][1] + b2v.y);
      yv.z = ev.z * fsig(gv.z + acc2[i][2] + b2v.z);
      yv.w = ev.w * fsig(gv.w + acc2[i][3] + b2v.w);
      st4bf(pk + (size_t)n * PK_STRIDE + SLOT_Y2 + tx * 4, yv);
    }
  }
}

// ------- fused 3-branch SpMM + edge-MLP + dinv + residual + out -------
// OUTM: 0 = no out;  1 = out = emb0 + rc + en (L=2 final);
//       2 = out = rc + en (generic first); 3 = out += en (generic accumulate)
template <int FIRST, int OUTM>
__global__ __launch_bounds__(256) void spmm3f_k(const int* __restrict__ rp,
    const int* __restrict__ rorder,
    const int2* __restrict__ ep, const float* __restrict__ cgum,
    const unsigned short* __restrict__ pk, const unsigned short* __restrict__ xhb,
    const float* __restrict__ b1, const float* __restrict__ W2,
    const float* __restrict__ b2, const float* __restrict__ emb0,
    unsigned short* __restrict__ pkn,
    float* __restrict__ out0, float* __restrict__ out1, float* __restrict__ out2,
    int N) {
  int g = threadIdx.x >> 4;
  int l = threadIdx.x & 15;
  int gid = blockIdx.x * 16 + g;
  if (gid >= N) return;
  int n = rorder[gid];
  int jb = rp[n], je = rp[n + 1];
  size_t o64 = (size_t)n * 64 + l * 4;
  size_t opk = (size_t)n * PK_STRIDE + l * 4;
  float4 xh4 = ldbf4(xhb + o64);
  float4 b1v = *(const float4*)(b1 + l * 4);
  float4 w2v = *(const float4*)(W2 + l * 4);
  float b2s = b2[0];
  float4 rc0, rc1, rc2;
  if (FIRST) {
    rc0 = *(const float4*)(emb0 + o64);
    rc1 = rc0; rc2 = rc0;
  } else {
    rc0 = ldbf4(pk + opk + SLOT_E0);
    rc1 = ldbf4(pk + opk + SLOT_E1);
    rc2 = ldbf4(pk + opk + SLOT_E2);
  }
  float4 acc0 = f4z(), acc1 = f4z(), acc2 = f4z();
  float wsum = 0.f;
  for (int base = jb; base < je; base += 16) {
    int idx = base + l;
    bool valid = idx < je;
    int2 ev = valid ? ep[idx] : make_int2(0, 0);
    float guv = valid ? cgum[idx] : 0.f;
    int cnt = min(16, je - base);
    int toff = __shfl(ev.x, 0, 16);
    const unsigned short* pr = pk + (size_t)toff + l * 4;
    ushort4 a0 = *(const ushort4*)(pr + SLOT_E0);
    ushort4 a1;
    if (!FIRST) a1 = *(const ushort4*)(pr + SLOT_E1);
    ushort4 a2 = *(const ushort4*)(pr + SLOT_Y2);
    ushort4 a3 = *(const ushort4*)(pr + SLOT_XT);
    for (int i = 0; i < cnt; i++) {
      ushort4 p0, p1, p2, p3;
      bool pf = (i + 1 < cnt);
      if (pf) {
        int toff2 = __shfl(ev.x, i + 1, 16);
        const unsigned short* pr2 = pk + (size_t)toff2 + l * 4;
        p0 = *(const ushort4*)(pr2 + SLOT_E0);
        if (!FIRST) p1 = *(const ushort4*)(pr2 + SLOT_E1);
        p2 = *(const ushort4*)(pr2 + SLOT_Y2);
        p3 = *(const ushort4*)(pr2 + SLOT_XT);
      }
      float gg = __shfl(__int_as_float(ev.y), i, 16);
      float gu = __shfl(guv, i, 16);
      float4 v0 = cvt4(a0);
      float4 v1 = FIRST ? v0 : cvt4(a1);
      float4 vy = cvt4(a2);
      float4 xt = cvt4(a3);
      float p = fmaxf(xh4.x + xt.x + b1v.x, 0.f) * w2v.x
              + fmaxf(xh4.y + xt.y + b1v.y, 0.f) * w2v.y
              + fmaxf(xh4.z + xt.z + b1v.z, 0.f) * w2v.z
              + fmaxf(xh4.w + xt.w + b1v.w, 0.f) * w2v.w;
      p += __shfl_xor(p, 1, 16);
      p += __shfl_xor(p, 2, 16);
      p += __shfl_xor(p, 4, 16);
      p += __shfl_xor(p, 8, 16);
      float w = fsig(gu + p + b2s);
      wsum += w;
      fma4(acc0, gg, v0);
      fma4(acc1, w, v1);
      fma4(acc2, gg, vy);
      if (pf) { a0 = p0; if (!FIRST) a1 = p1; a2 = p2; a3 = p3; }
    }
  }
  float dinv = (wsum > 0.f) ? __builtin_amdgcn_rcpf(wsum) : 0.f;
  float4 en0 = add4(acc0, rc0);
  acc1.x *= dinv; acc1.y *= dinv; acc1.z *= dinv; acc1.w *= dinv;
  float4 en1 = add4(acc1, rc1);
  float4 en2 = add4(acc2, rc2);
  unsigned short* pn = pkn + opk;
  st4bf(pn + SLOT_E0, en0);
  st4bf(pn + SLOT_E1, en1);
  st4bf(pn + SLOT_E2, en2);
  if (OUTM == 1) {
    float4 base = *(const float4*)(emb0 + o64);
    *(float4*)(out0 + o64) = add4(base, add4(rc0, en0));
    *(float4*)(out1 + o64) = add4(base, add4(rc1, en1));
    *(float4*)(out2 + o64) = add4(base, add4(rc2, en2));
  } else if (OUTM == 2) {
    *(float4*)(out0 + o64) = add4(rc0, en0);
    *(float4*)(out1 + o64) = add4(rc1, en1);
    *(float4*)(out2 + o64) = add4(rc2, en2);
  } else if (OUTM == 3) {
    *(float4*)(out0 + o64) = add4(*(const float4*)(out0 + o64), en0);
    *(float4*)(out1 + o64) = add4(*(const float4*)(out1 + o64), en1);
    *(float4*)(out2 + o64) = add4(*(const float4*)(out2 + o64), en2);
  }
}

extern "C" void kernel_launch(void* const* d_in, const int* in_sizes, int n_in,
                              void* d_out, int out_size, void* d_ws, size_t ws_size,
                              hipStream_t stream) {
  const float* emb0        = (const float*)d_in[0];
  const int*   h_idx       = (const int*)d_in[1];
  const int*   t_idx       = (const int*)d_in[2];
  const float* G_values    = (const float*)d_in[3];
  const float* edge_gumbel = (const float*)d_in[4];
  const float* emb_gumbel  = (const float*)d_in[5];
  const float* edge_W1     = (const float*)d_in[6];
  const float* edge_b1     = (const float*)d_in[7];
  const float* edge_W2     = (const float*)d_in[8];
  const float* edge_b2     = (const float*)d_in[9];
  const float* emb_W1      = (const float*)d_in[10];
  const float* emb_b1      = (const float*)d_in[11];
  const float* emb_W2      = (const float*)d_in[12];
  const float* emb_b2      = (const float*)d_in[13];

  const int D = 64;
  const int N = in_sizes[0] / D;
  const int E = in_sizes[1];
  const int L = in_sizes[4] / E;
  const size_t ND = (size_t)N * D;

  char* p = (char*)d_ws;
  auto alloc = [&](size_t bytes) -> char* {
    char* r = p;
    p += (bytes + 255) & ~(size_t)255;
    return r;
  };
  unsigned short* xhb = (unsigned short*)alloc(ND * 2);
  unsigned short* pkA = (unsigned short*)alloc((size_t)N * PK_STRIDE * 2);
  unsigned short* pkB = (unsigned short*)alloc((size_t)N * PK_STRIDE * 2);
  int2*  ep    = (int2*)alloc((size_t)E * 8);
  float* cgum  = (float*)alloc((size_t)L * E * 4);
  int*   deg   = (int*)alloc(((size_t)N + 128) * 4);   // deg[N] | bins[64] | cur2[64]
  int*   bins  = deg + N;
  int*   cur2  = deg + N + 64;
  int*   cur   = (int*)alloc((size_t)N * 4);
  int*   rp    = (int*)alloc(((size_t)N + 1) * 4);
  int*   perm  = (int*)alloc((size_t)E * 4);
  int*   rorder = (int*)alloc((size_t)N * 4);
  int*   sums  = (int*)alloc(1024 * 4);

  float* out = (float*)d_out;

  init_k<<<(N * 16 + 255) / 256, 256, 0, stream>>>(emb0, pkA, N);
  hipMemsetAsync(deg, 0, ((size_t)N + 128) * 4, stream);
  hist_k<<<(E + 255) / 256, 256, 0, stream>>>(h_idx, deg, E);
  int nch = (N + 1023) / 1024;
  scanA_k<<<nch, 1024, 0, stream>>>(deg, rp, sums, N);
  scanB_k<<<1, 64, 0, stream>>>(sums, nch);
  scanC_k<<<(N + 256) / 256, 256, 0, stream>>>(rp, cur, sums, N, E);
  fill_k<<<(E + 255) / 256, 256, 0, stream>>>(h_idx, cur, perm, E);
  dhist_k<<<(N + 255) / 256, 256, 0, stream>>>(deg, bins, N);
  dscan_k<<<1, 64, 0, stream>>>(bins, cur2);
  dscatter_k<<<(N + 255) / 256, 256, 0, stream>>>(deg, cur2, rorder, N);
  pregather_k<<<(E + 255) / 256, 256, 0, stream>>>(perm, t_idx, G_values,
                                                   edge_gumbel, ep, cgum, E, L);

  int nb64 = (N + 63) / 64;
  int nb16 = (N + 15) / 16;

  for (int i = 0; i < L; i++) {
    unsigned short* pkc = (i & 1) ? pkB : pkA;
    unsigned short* pkn = (i & 1) ? pkA : pkB;
    xht_k<<<nb64, 256, 0, stream>>>(pkc, edge_W1 + (size_t)i * 128 * 64, xhb, pkc, N);
    mlp2_k<<<nb64, 256, 0, stream>>>(pkc, emb_W1 + (size_t)i * 4096,
                                     emb_b1 + (size_t)i * 64,
                                     emb_W2 + (size_t)i * 4096,
                                     emb_b2 + (size_t)i * 64,
                                     emb_gumbel + (size_t)i * ND, pkc, N);
    const float* cg = cgum + (size_t)i * E;
    const float* eb1 = edge_b1 + (size_t)i * 64;
    const float* eW2 = edge_W2 + (size_t)i * 64;
    const float* eb2 = edge_b2 + i;
    if (L == 2) {
      if (i == 0)
        spmm3f_k<1, 0><<<nb16, 256, 0, stream>>>(rp, rorder, ep, cg, pkc, xhb,
                                                 eb1, eW2, eb2, emb0, pkn,
                                                 out, out + ND, out + 2 * ND, N);
      else
        spmm3f_k<0, 1><<<nb16, 256, 0, stream>>>(rp, rorder, ep, cg, pkc, xhb,
                                                 eb1, eW2, eb2, emb0, pkn,
                                                 out, out + ND, out + 2 * ND, N);
    } else {
      if (i == 0)
        spmm3f_k<1, 2><<<nb16, 256, 0, stream>>>(rp, rorder, ep, cg, pkc, xhb,
                                                 eb1, eW2, eb2, emb0, pkn,
                                                 out, out + ND, out + 2 * ND, N);
      else
        spmm3f_k<0, 3><<<nb16, 256, 0, stream>>>(rp, rorder, ep, cg, pkc, xhb,
                                                 eb1, eW2, eb2, emb0, pkn,
                                                 out, out + ND, out + 2 * ND, N);
    }
  }
}

// Round 6
// 478.732 us; speedup vs baseline: 1.7123x; 1.7123x over previous
//
#include <hip/hip_runtime.h>
#include <hip/hip_bf16.h>
#include <math.h>

#define ST_E 68
#define ST_W 68
#define ST_WX 132

// pk row layout (bf16 elements): [e0|e1|y2|xt|e2], stride 320
#define SLOT_E0 0
#define SLOT_E1 64
#define SLOT_Y2 128
#define SLOT_XT 192
#define SLOT_E2 256
#define PK_STRIDE 320

__device__ __forceinline__ float4 f4z() { return make_float4(0.f, 0.f, 0.f, 0.f); }
__device__ __forceinline__ void fma4(float4& a, float s, const float4& v) {
  a.x = fmaf(s, v.x, a.x); a.y = fmaf(s, v.y, a.y);
  a.z = fmaf(s, v.z, a.z); a.w = fmaf(s, v.w, a.w);
}
__device__ __forceinline__ float4 add4(const float4& a, const float4& b) {
  return make_float4(a.x + b.x, a.y + b.y, a.z + b.z, a.w + b.w);
}
__device__ __forceinline__ float4 cvt4(const ushort4& u) {
  float4 f;
  f.x = __uint_as_float((unsigned)u.x << 16);
  f.y = __uint_as_float((unsigned)u.y << 16);
  f.z = __uint_as_float((unsigned)u.z << 16);
  f.w = __uint_as_float((unsigned)u.w << 16);
  return f;
}
__device__ __forceinline__ float4 ldbf4(const unsigned short* p) {
  return cvt4(*(const ushort4*)p);
}
__device__ __forceinline__ unsigned short f2bf(float v) {
  __hip_bfloat16 h = __float2bfloat16(v);
  return *reinterpret_cast<unsigned short*>(&h);
}
__device__ __forceinline__ void st4bf(unsigned short* p, const float4& v) {
  ushort4 u;
  u.x = f2bf(v.x); u.y = f2bf(v.y); u.z = f2bf(v.z); u.w = f2bf(v.w);
  *(ushort4*)p = u;
}
__device__ __forceinline__ float fsig(float x) {    // sigmoid, fast
  return __builtin_amdgcn_rcpf(1.f + __expf(-x));
}

// -------- init: pk0 e0/e1/e2 slots = bf16(emb0) --------
__global__ void init_k(const float* __restrict__ emb0, unsigned short* __restrict__ pk0,
                       int N) {
  int idx = blockIdx.x * blockDim.x + threadIdx.x;
  int n = idx >> 4, q = idx & 15;
  if (n >= N) return;
  float4 v = *(const float4*)(emb0 + (size_t)n * 64 + q * 4);
  unsigned short* r = pk0 + (size_t)n * PK_STRIDE + q * 4;
  st4bf(r + SLOT_E0, v);
  st4bf(r + SLOT_E1, v);
  st4bf(r + SLOT_E2, v);
}

// ---------------- CSR build ----------------
__global__ void hist_k(const int* __restrict__ h, int* __restrict__ deg, int E) {
  int i = blockIdx.x * blockDim.x + threadIdx.x;
  if (i < E) atomicAdd(&deg[h[i]], 1);
}

__global__ void scanA_k(const int* __restrict__ deg, int* __restrict__ rp,
                        int* __restrict__ sums, int N) {
  __shared__ int s[1024];
  int i = blockIdx.x * 1024 + threadIdx.x;
  int v = (i < N) ? deg[i] : 0;
  s[threadIdx.x] = v;
  __syncthreads();
  for (int off = 1; off < 1024; off <<= 1) {
    int t = (threadIdx.x >= (unsigned)off) ? s[threadIdx.x - off] : 0;
    __syncthreads();
    s[threadIdx.x] += t;
    __syncthreads();
  }
  if (i < N) rp[i] = s[threadIdx.x] - v;
  if (threadIdx.x == 1023) sums[blockIdx.x] = s[1023];
}

// one-wave exclusive scan over nch chunk sums
__global__ void scanB_k(int* sums, int nch) {
  int lane = threadIdx.x;   // 64 threads
  int run = 0;
  for (int base = 0; base < nch; base += 64) {
    int v = (base + lane < nch) ? sums[base + lane] : 0;
    int incl = v;
    for (int off = 1; off < 64; off <<= 1) {
      int t = __shfl_up(incl, off, 64);
      if (lane >= off) incl += t;
    }
    if (base + lane < nch) sums[base + lane] = run + (incl - v);
    run += __shfl(incl, 63, 64);
  }
}

__global__ void scanC_k(int* __restrict__ rp, int* __restrict__ cur,
                        const int* __restrict__ sums, int N, int E) {
  int i = blockIdx.x * blockDim.x + threadIdx.x;
  if (i < N) {
    int v = rp[i] + sums[i >> 10];
    rp[i] = v; cur[i] = v;
  } else if (i == N) {
    rp[N] = E;
  }
}

__global__ void fill_k(const int* __restrict__ h, int* __restrict__ cur,
                       int* __restrict__ perm, int E) {
  int i = blockIdx.x * blockDim.x + threadIdx.x;
  if (i < E) {
    int pos = atomicAdd(&cur[h[i]], 1);
    perm[pos] = i;
  }
}

// ------- degree-balanced row order: counting sort by degree, descending -------
__device__ __forceinline__ int degbin(int d) { return 63 - min(d, 63); }

__global__ void dhist_k(const int* __restrict__ deg, int* __restrict__ bins, int N) {
  __shared__ int h[64];
  if (threadIdx.x < 64) h[threadIdx.x] = 0;
  __syncthreads();
  int i = blockIdx.x * blockDim.x + threadIdx.x;
  if (i < N) atomicAdd(&h[degbin(deg[i])], 1);
  __syncthreads();
  if (threadIdx.x < 64 && h[threadIdx.x]) atomicAdd(&bins[threadIdx.x], h[threadIdx.x]);
}

__global__ void dscan_k(const int* __restrict__ bins, int* __restrict__ cur2) {
  int lane = threadIdx.x;  // 64
  int v = bins[lane];
  int incl = v;
  for (int off = 1; off < 64; off <<= 1) {
    int t = __shfl_up(incl, off, 64);
    if (lane >= off) incl += t;
  }
  cur2[lane] = incl - v;
}

// LDS-aggregated scatter: local rank via LDS atomics, one global atomic
// per (block, bin) — fixes the 64-address global contention (G12).
__global__ void dscatter_k(const int* __restrict__ deg, int* __restrict__ cur2,
                           int* __restrict__ rorder, int N) {
  __shared__ int lcount[64];
  __shared__ int lbase[64];
  if (threadIdx.x < 64) lcount[threadIdx.x] = 0;
  __syncthreads();
  int i = blockIdx.x * blockDim.x + threadIdx.x;
  int bin = 0, lrank = 0;
  bool valid = i < N;
  if (valid) {
    bin = degbin(deg[i]);
    lrank = atomicAdd(&lcount[bin], 1);
  }
  __syncthreads();
  if (threadIdx.x < 64) {
    int c = lcount[threadIdx.x];
    lbase[threadIdx.x] = c ? atomicAdd(&cur2[threadIdx.x], c) : 0;
  }
  __syncthreads();
  if (valid) rorder[lbase[bin] + lrank] = i;
}

// ------- pre-gather edge data into CSR slot order; t pre-scaled by PK_STRIDE -------
__global__ void pregather_k(const int* __restrict__ perm, const int* __restrict__ t_idx,
                            const float* __restrict__ G, const float* __restrict__ gum,
                            int2* __restrict__ ep, float* __restrict__ cgum,
                            int E, int L) {
  int j = blockIdx.x * blockDim.x + threadIdx.x;
  if (j < E) {
    int pe = perm[j];
    ep[j] = make_int2(t_idx[pe] * PK_STRIDE, __float_as_int(G[pe]));
    for (int l = 0; l < L; l++) cgum[(size_t)l * E + j] = gum[(size_t)l * E + pe];
  }
}

// ------- xht: xhb[N][64] bf16, xt -> pk XT slot (reads e1 from pk) -------
__global__ __launch_bounds__(256) void xht_k(const unsigned short* __restrict__ pkin,
                                             const float* __restrict__ W,  // [128][64]
                                             unsigned short* __restrict__ xhb,
                                             unsigned short* __restrict__ pk, int N) {
  __shared__ float et[64 * ST_E];
  __shared__ float wl[64 * ST_WX];
  int tid = threadIdx.x;
  int n0 = blockIdx.x * 64;
  for (int i = tid; i < 64 * 16; i += 256) {
    int r = i >> 4, c4 = (i & 15) * 4;
    float4 v = (n0 + r < N)
        ? ldbf4(pkin + (size_t)(n0 + r) * PK_STRIDE + SLOT_E1 + c4) : f4z();
    *(float4*)(et + r * ST_E + c4) = v;
  }
  for (int i = tid; i < 128 * 16; i += 256) {
    int r = i >> 4, c4 = (i & 15) * 4;
    float4 v = *(const float4*)(W + r * 64 + c4);
    if (r < 64) *(float4*)(wl + r * ST_WX + c4) = v;
    else        *(float4*)(wl + (r - 64) * ST_WX + 64 + c4) = v;
  }
  __syncthreads();
  int rg = tid >> 4, tx = tid & 15;
  int s2 = (tx >> 2) * 2;
  float acc[4][8];
#pragma unroll
  for (int i = 0; i < 4; i++)
#pragma unroll
    for (int j = 0; j < 8; j++) acc[i][j] = 0.f;
#pragma unroll 4
  for (int k = 0; k < 64; k++) {
    int kk = (k + s2) & 63;
    float a0 = et[(rg * 4 + 0) * ST_E + kk];
    float a1 = et[(rg * 4 + 1) * ST_E + kk];
    float a2 = et[(rg * 4 + 2) * ST_E + kk];
    float a3 = et[(rg * 4 + 3) * ST_E + kk];
    float4 b0 = *(const float4*)(wl + kk * ST_WX + tx * 8);
    float4 b1 = *(const float4*)(wl + kk * ST_WX + tx * 8 + 4);
    acc[0][0] = fmaf(a0, b0.x, acc[0][0]); acc[0][1] = fmaf(a0, b0.y, acc[0][1]);
    acc[0][2] = fmaf(a0, b0.z, acc[0][2]); acc[0][3] = fmaf(a0, b0.w, acc[0][3]);
    acc[0][4] = fmaf(a0, b1.x, acc[0][4]); acc[0][5] = fmaf(a0, b1.y, acc[0][5]);
    acc[0][6] = fmaf(a0, b1.z, acc[0][6]); acc[0][7] = fmaf(a0, b1.w, acc[0][7]);
    acc[1][0] = fmaf(a1, b0.x, acc[1][0]); acc[1][1] = fmaf(a1, b0.y, acc[1][1]);
    acc[1][2] = fmaf(a1, b0.z, acc[1][2]); acc[1][3] = fmaf(a1, b0.w, acc[1][3]);
    acc[1][4] = fmaf(a1, b1.x, acc[1][4]); acc[1][5] = fmaf(a1, b1.y, acc[1][5]);
    acc[1][6] = fmaf(a1, b1.z, acc[1][6]); acc[1][7] = fmaf(a1, b1.w, acc[1][7]);
    acc[2][0] = fmaf(a2, b0.x, acc[2][0]); acc[2][1] = fmaf(a2, b0.y, acc[2][1]);
    acc[2][2] = fmaf(a2, b0.z, acc[2][2]); acc[2][3] = fmaf(a2, b0.w, acc[2][3]);
    acc[2][4] = fmaf(a2, b1.x, acc[2][4]); acc[2][5] = fmaf(a2, b1.y, acc[2][5]);
    acc[2][6] = fmaf(a2, b1.z, acc[2][6]); acc[2][7] = fmaf(a2, b1.w, acc[2][7]);
    acc[3][0] = fmaf(a3, b0.x, acc[3][0]); acc[3][1] = fmaf(a3, b0.y, acc[3][1]);
    acc[3][2] = fmaf(a3, b0.z, acc[3][2]); acc[3][3] = fmaf(a3, b0.w, acc[3][3]);
    acc[3][4] = fmaf(a3, b1.x, acc[3][4]); acc[3][5] = fmaf(a3, b1.y, acc[3][5]);
    acc[3][6] = fmaf(a3, b1.z, acc[3][6]); acc[3][7] = fmaf(a3, b1.w, acc[3][7]);
  }
#pragma unroll
  for (int i = 0; i < 4; i++) {
    int n = n0 + rg * 4 + i;
    if (n < N) {
      if (tx < 8) {
        unsigned short* xp = xhb + (size_t)n * 64 + tx * 8;
        st4bf(xp, make_float4(acc[i][0], acc[i][1], acc[i][2], acc[i][3]));
        st4bf(xp + 4, make_float4(acc[i][4], acc[i][5], acc[i][6], acc[i][7]));
      } else {
        unsigned short* pp = pk + (size_t)n * PK_STRIDE + SLOT_XT + (tx - 8) * 8;
        st4bf(pp, make_float4(acc[i][0], acc[i][1], acc[i][2], acc[i][3]));
        st4bf(pp + 4, make_float4(acc[i][4], acc[i][5], acc[i][6], acc[i][7]));
      }
    }
  }
}

// ------- node MLP + gate: pk Y2 slot = bf16(sigmoid(gum+mlp(e2))*e2) -------
__global__ __launch_bounds__(256) void mlp2_k(const unsigned short* __restrict__ pkin,
    const float* __restrict__ W1, const float* __restrict__ b1,
    const float* __restrict__ W2, const float* __restrict__ b2,
    const float* __restrict__ gum, unsigned short* __restrict__ pk, int N) {
  __shared__ float et[64 * ST_E];
  __shared__ float w1l[64 * ST_W];
  __shared__ float w2l[64 * ST_W];
  __shared__ float ht[64 * ST_E];
  int tid = threadIdx.x;
  int n0 = blockIdx.x * 64;
  for (int i = tid; i < 64 * 16; i += 256) {
    int r = i >> 4, c4 = (i & 15) * 4;
    float4 v = (n0 + r < N)
        ? ldbf4(pkin + (size_t)(n0 + r) * PK_STRIDE + SLOT_E2 + c4) : f4z();
    *(float4*)(et + r * ST_E + c4) = v;
    *(float4*)(w1l + r * ST_W + c4) = *(const float4*)(W1 + r * 64 + c4);
    *(float4*)(w2l + r * ST_W + c4) = *(const float4*)(W2 + r * 64 + c4);
  }
  __syncthreads();
  int rg = tid >> 4, tx = tid & 15;
  int s2 = (tx >> 2) * 2;
  float acc[4][4];
#pragma unroll
  for (int i = 0; i < 4; i++)
#pragma unroll
    for (int j = 0; j < 4; j++) acc[i][j] = 0.f;
#pragma unroll 4
  for (int k = 0; k < 64; k++) {
    int kk = (k + s2) & 63;
    float a0 = et[(rg * 4 + 0) * ST_E + kk];
    float a1 = et[(rg * 4 + 1) * ST_E + kk];
    float a2 = et[(rg * 4 + 2) * ST_E + kk];
    float a3 = et[(rg * 4 + 3) * ST_E + kk];
    float4 bv = *(const float4*)(w1l + kk * ST_W + tx * 4);
    acc[0][0] = fmaf(a0, bv.x, acc[0][0]); acc[0][1] = fmaf(a0, bv.y, acc[0][1]);
    acc[0][2] = fmaf(a0, bv.z, acc[0][2]); acc[0][3] = fmaf(a0, bv.w, acc[0][3]);
    acc[1][0] = fmaf(a1, bv.x, acc[1][0]); acc[1][1] = fmaf(a1, bv.y, acc[1][1]);
    acc[1][2] = fmaf(a1, bv.z, acc[1][2]); acc[1][3] = fmaf(a1, bv.w, acc[1][3]);
    acc[2][0] = fmaf(a2, bv.x, acc[2][0]); acc[2][1] = fmaf(a2, bv.y, acc[2][1]);
    acc[2][2] = fmaf(a2, bv.z, acc[2][2]); acc[2][3] = fmaf(a2, bv.w, acc[2][3]);
    acc[3][0] = fmaf(a3, bv.x, acc[3][0]); acc[3][1] = fmaf(a3, bv.y, acc[3][1]);
    acc[3][2] = fmaf(a3, bv.z, acc[3][2]); acc[3][3] = fmaf(a3, bv.w, acc[3][3]);
  }
  float4 b1v = *(const float4*)(b1 + tx * 4);
#pragma unroll
  for (int i = 0; i < 4; i++) {
    float4 hv = make_float4(fmaxf(acc[i][0] + b1v.x, 0.f), fmaxf(acc[i][1] + b1v.y, 0.f),
                            fmaxf(acc[i][2] + b1v.z, 0.f), fmaxf(acc[i][3] + b1v.w, 0.f));
    *(float4*)(ht + (rg * 4 + i) * ST_E + tx * 4) = hv;
  }
  __syncthreads();
  float acc2[4][4];
#pragma unroll
  for (int i = 0; i < 4; i++)
#pragma unroll
    for (int j = 0; j < 4; j++) acc2[i][j] = 0.f;
#pragma unroll 4
  for (int k = 0; k < 64; k++) {
    int kk = (k + s2) & 63;
    float a0 = ht[(rg * 4 + 0) * ST_E + kk];
    float a1 = ht[(rg * 4 + 1) * ST_E + kk];
    float a2 = ht[(rg * 4 + 2) * ST_E + kk];
    float a3 = ht[(rg * 4 + 3) * ST_E + kk];
    float4 bv = *(const float4*)(w2l + kk * ST_W + tx * 4);
    acc2[0][0] = fmaf(a0, bv.x, acc2[0][0]); acc2[0][1] = fmaf(a0, bv.y, acc2[0][1]);
    acc2[0][2] = fmaf(a0, bv.z, acc2[0][2]); acc2[0][3] = fmaf(a0, bv.w, acc2[0][3]);
    acc2[1][0] = fmaf(a1, bv.x, acc2[1][0]); acc2[1][1] = fmaf(a1, bv.y, acc2[1][1]);
    acc2[1][2] = fmaf(a1, bv.z, acc2[1][2]); acc2[1][3] = fmaf(a1, bv.w, acc2[1][3]);
    acc2[2][0] = fmaf(a2, bv.x, acc2[2][0]); acc2[2][1] = fmaf(a2, bv.y, acc2[2][1]);
    acc2[2][2] = fmaf(a2, bv.z, acc2[2][2]); acc2[2][3] = fmaf(a2, bv.w, acc2[2][3]);
    acc2[3][0] = fmaf(a3, bv.x, acc2[3][0]); acc2[3][1] = fmaf(a3, bv.y, acc2[3][1]);
    acc2[3][2] = fmaf(a3, bv.z, acc2[3][2]); acc2[3][3] = fmaf(a3, bv.w, acc2[3][3]);
  }
  float4 b2v = *(const float4*)(b2 + tx * 4);
#pragma unroll
  for (int i = 0; i < 4; i++) {
    int n = n0 + rg * 4 + i;
    if (n < N) {
      float4 gv = *(const float4*)(gum + (size_t)n * 64 + tx * 4);
      float4 ev = *(const float4*)(et + (rg * 4 + i) * ST_E + tx * 4);
      float4 yv;
      yv.x = ev.x * fsig(gv.x + acc2[i][0] + b2v.x);
      yv.y = ev.y * fsig(gv.y + acc2[i][1] + b2v.y);
      yv.z = ev.z * fsig(gv.z + acc2[i][2] + b2v.z);
      yv.w = ev.w * fsig(gv.w + acc2[i][3] + b2v.w);
      st4bf(pk + (size_t)n * PK_STRIDE + SLOT_Y2 + tx * 4, yv);
    }
  }
}

// ------- fused 3-branch SpMM + edge-MLP + dinv + residual + out -------
// OUTM: 0 = no out;  1 = out = emb0 + rc + en (L=2 final);
//       2 = out = rc + en (generic first); 3 = out += en (generic accumulate)
template <int FIRST, int OUTM>
__global__ __launch_bounds__(256) void spmm3f_k(const int* __restrict__ rp,
    const int* __restrict__ rorder,
    const int2* __restrict__ ep, const float* __restrict__ cgum,
    const unsigned short* __restrict__ pk, const unsigned short* __restrict__ xhb,
    const float* __restrict__ b1, const float* __restrict__ W2,
    const float* __restrict__ b2, const float* __restrict__ emb0,
    unsigned short* __restrict__ pkn,
    float* __restrict__ out0, float* __restrict__ out1, float* __restrict__ out2,
    int N) {
  int g = threadIdx.x >> 4;
  int l = threadIdx.x & 15;
  int gid = blockIdx.x * 16 + g;
  if (gid >= N) return;
  int n = rorder[gid];
  int jb = rp[n], je = rp[n + 1];
  size_t o64 = (size_t)n * 64 + l * 4;
  size_t opk = (size_t)n * PK_STRIDE + l * 4;
  float4 xh4 = ldbf4(xhb + o64);
  float4 b1v = *(const float4*)(b1 + l * 4);
  float4 w2v = *(const float4*)(W2 + l * 4);
  float b2s = b2[0];
  float4 rc0, rc1, rc2;
  if (FIRST) {
    rc0 = *(const float4*)(emb0 + o64);
    rc1 = rc0; rc2 = rc0;
  } else {
    rc0 = ldbf4(pk + opk + SLOT_E0);
    rc1 = ldbf4(pk + opk + SLOT_E1);
    rc2 = ldbf4(pk + opk + SLOT_E2);
  }
  float4 acc0 = f4z(), acc1 = f4z(), acc2 = f4z();
  float wsum = 0.f;
  for (int base = jb; base < je; base += 16) {
    int idx = base + l;
    bool valid = idx < je;
    int2 ev = valid ? ep[idx] : make_int2(0, 0);
    float guv = valid ? cgum[idx] : 0.f;
    int cnt = min(16, je - base);
    int toff = __shfl(ev.x, 0, 16);
    const unsigned short* pr = pk + (size_t)toff + l * 4;
    ushort4 a0 = *(const ushort4*)(pr + SLOT_E0);
    ushort4 a1;
    if (!FIRST) a1 = *(const ushort4*)(pr + SLOT_E1);
    ushort4 a2 = *(const ushort4*)(pr + SLOT_Y2);
    ushort4 a3 = *(const ushort4*)(pr + SLOT_XT);
    for (int i = 0; i < cnt; i++) {
      ushort4 p0, p1, p2, p3;
      bool pf = (i + 1 < cnt);
      if (pf) {
        int toff2 = __shfl(ev.x, i + 1, 16);
        const unsigned short* pr2 = pk + (size_t)toff2 + l * 4;
        p0 = *(const ushort4*)(pr2 + SLOT_E0);
        if (!FIRST) p1 = *(const ushort4*)(pr2 + SLOT_E1);
        p2 = *(const ushort4*)(pr2 + SLOT_Y2);
        p3 = *(const ushort4*)(pr2 + SLOT_XT);
      }
      float gg = __shfl(__int_as_float(ev.y), i, 16);
      float gu = __shfl(guv, i, 16);
      float4 v0 = cvt4(a0);
      float4 v1 = FIRST ? v0 : cvt4(a1);
      float4 vy = cvt4(a2);
      float4 xt = cvt4(a3);
      float p = fmaxf(xh4.x + xt.x + b1v.x, 0.f) * w2v.x
              + fmaxf(xh4.y + xt.y + b1v.y, 0.f) * w2v.y
              + fmaxf(xh4.z + xt.z + b1v.z, 0.f) * w2v.z
              + fmaxf(xh4.w + xt.w + b1v.w, 0.f) * w2v.w;
      p += __shfl_xor(p, 1, 16);
      p += __shfl_xor(p, 2, 16);
      p += __shfl_xor(p, 4, 16);
      p += __shfl_xor(p, 8, 16);
      float w = fsig(gu + p + b2s);
      wsum += w;
      fma4(acc0, gg, v0);
      fma4(acc1, w, v1);
      fma4(acc2, gg, vy);
      if (pf) { a0 = p0; if (!FIRST) a1 = p1; a2 = p2; a3 = p3; }
    }
  }
  float dinv = (wsum > 0.f) ? __builtin_amdgcn_rcpf(wsum) : 0.f;
  float4 en0 = add4(acc0, rc0);
  acc1.x *= dinv; acc1.y *= dinv; acc1.z *= dinv; acc1.w *= dinv;
  float4 en1 = add4(acc1, rc1);
  float4 en2 = add4(acc2, rc2);
  unsigned short* pn = pkn + opk;
  st4bf(pn + SLOT_E0, en0);
  st4bf(pn + SLOT_E1, en1);
  st4bf(pn + SLOT_E2, en2);
  if (OUTM == 1) {
    float4 base = *(const float4*)(emb0 + o64);
    *(float4*)(out0 + o64) = add4(base, add4(rc0, en0));
    *(float4*)(out1 + o64) = add4(base, add4(rc1, en1));
    *(float4*)(out2 + o64) = add4(base, add4(rc2, en2));
  } else if (OUTM == 2) {
    *(float4*)(out0 + o64) = add4(rc0, en0);
    *(float4*)(out1 + o64) = add4(rc1, en1);
    *(float4*)(out2 + o64) = add4(rc2, en2);
  } else if (OUTM == 3) {
    *(float4*)(out0 + o64) = add4(*(const float4*)(out0 + o64), en0);
    *(float4*)(out1 + o64) = add4(*(const float4*)(out1 + o64), en1);
    *(float4*)(out2 + o64) = add4(*(const float4*)(out2 + o64), en2);
  }
}

extern "C" void kernel_launch(void* const* d_in, const int* in_sizes, int n_in,
                              void* d_out, int out_size, void* d_ws, size_t ws_size,
                              hipStream_t stream) {
  const float* emb0        = (const float*)d_in[0];
  const int*   h_idx       = (const int*)d_in[1];
  const int*   t_idx       = (const int*)d_in[2];
  const float* G_values    = (const float*)d_in[3];
  const float* edge_gumbel = (const float*)d_in[4];
  const float* emb_gumbel  = (const float*)d_in[5];
  const float* edge_W1     = (const float*)d_in[6];
  const float* edge_b1     = (const float*)d_in[7];
  const float* edge_W2     = (const float*)d_in[8];
  const float* edge_b2     = (const float*)d_in[9];
  const float* emb_W1      = (const float*)d_in[10];
  const float* emb_b1      = (const float*)d_in[11];
  const float* emb_W2      = (const float*)d_in[12];
  const float* emb_b2      = (const float*)d_in[13];

  const int D = 64;
  const int N = in_sizes[0] / D;
  const int E = in_sizes[1];
  const int L = in_sizes[4] / E;
  const size_t ND = (size_t)N * D;

  char* p = (char*)d_ws;
  auto alloc = [&](size_t bytes) -> char* {
    char* r = p;
    p += (bytes + 255) & ~(size_t)255;
    return r;
  };
  unsigned short* xhb = (unsigned short*)alloc(ND * 2);
  unsigned short* pkA = (unsigned short*)alloc((size_t)N * PK_STRIDE * 2);
  unsigned short* pkB = (unsigned short*)alloc((size_t)N * PK_STRIDE * 2);
  int2*  ep    = (int2*)alloc((size_t)E * 8);
  float* cgum  = (float*)alloc((size_t)L * E * 4);
  int*   deg   = (int*)alloc(((size_t)N + 128) * 4);   // deg[N] | bins[64] | cur2[64]
  int*   bins  = deg + N;
  int*   cur2  = deg + N + 64;
  int*   cur   = (int*)alloc((size_t)N * 4);
  int*   rp    = (int*)alloc(((size_t)N + 1) * 4);
  int*   perm  = (int*)alloc((size_t)E * 4);
  int*   rorder = (int*)alloc((size_t)N * 4);
  int*   sums  = (int*)alloc(1024 * 4);

  float* out = (float*)d_out;

  init_k<<<(N * 16 + 255) / 256, 256, 0, stream>>>(emb0, pkA, N);
  hipMemsetAsync(deg, 0, ((size_t)N + 128) * 4, stream);
  hist_k<<<(E + 255) / 256, 256, 0, stream>>>(h_idx, deg, E);
  int nch = (N + 1023) / 1024;
  scanA_k<<<nch, 1024, 0, stream>>>(deg, rp, sums, N);
  scanB_k<<<1, 64, 0, stream>>>(sums, nch);
  scanC_k<<<(N + 256) / 256, 256, 0, stream>>>(rp, cur, sums, N, E);
  fill_k<<<(E + 255) / 256, 256, 0, stream>>>(h_idx, cur, perm, E);
  dhist_k<<<(N + 255) / 256, 256, 0, stream>>>(deg, bins, N);
  dscan_k<<<1, 64, 0, stream>>>(bins, cur2);
  dscatter_k<<<(N + 255) / 256, 256, 0, stream>>>(deg, cur2, rorder, N);
  pregather_k<<<(E + 255) / 256, 256, 0, stream>>>(perm, t_idx, G_values,
                                                   edge_gumbel, ep, cgum, E, L);

  int nb64 = (N + 63) / 64;
  int nb16 = (N + 15) / 16;

  for (int i = 0; i < L; i++) {
    unsigned short* pkc = (i & 1) ? pkB : pkA;
    unsigned short* pkn = (i & 1) ? pkA : pkB;
    xht_k<<<nb64, 256, 0, stream>>>(pkc, edge_W1 + (size_t)i * 128 * 64, xhb, pkc, N);
    mlp2_k<<<nb64, 256, 0, stream>>>(pkc, emb_W1 + (size_t)i * 4096,
                                     emb_b1 + (size_t)i * 64,
                                     emb_W2 + (size_t)i * 4096,
                                     emb_b2 + (size_t)i * 64,
                                     emb_gumbel + (size_t)i * ND, pkc, N);
    const float* cg = cgum + (size_t)i * E;
    const float* eb1 = edge_b1 + (size_t)i * 64;
    const float* eW2 = edge_W2 + (size_t)i * 64;
    const float* eb2 = edge_b2 + i;
    if (L == 2) {
      if (i == 0)
        spmm3f_k<1, 0><<<nb16, 256, 0, stream>>>(rp, rorder, ep, cg, pkc, xhb,
                                                 eb1, eW2, eb2, emb0, pkn,
                                                 out, out + ND, out + 2 * ND, N);
      else
        spmm3f_k<0, 1><<<nb16, 256, 0, stream>>>(rp, rorder, ep, cg, pkc, xhb,
                                                 eb1, eW2, eb2, emb0, pkn,
                                                 out, out + ND, out + 2 * ND, N);
    } else {
      if (i == 0)
        spmm3f_k<1, 2><<<nb16, 256, 0, stream>>>(rp, rorder, ep, cg, pkc, xhb,
                                                 eb1, eW2, eb2, emb0, pkn,
                                                 out, out + ND, out + 2 * ND, N);
      else
        spmm3f_k<0, 3><<<nb16, 256, 0, stream>>>(rp, rorder, ep, cg, pkc, xhb,
                                                 eb1, eW2, eb2, emb0, pkn,
                                                 out, out + ND, out + 2 * ND, N);
    }
  }
}

// Round 7
// 471.957 us; speedup vs baseline: 1.7369x; 1.0144x over previous
//
#include <hip/hip_runtime.h>
#include <hip/hip_bf16.h>
#include <math.h>

#define ST_E 68
#define ST_W 68
#define ST_WX 132

// pk row: 256 bf16 = 512B, line-aligned.
//   elems 0..127  : E0E1 region, chunk l (l=0..15) = [e0[4l..4l+3] | e1[4l..4l+3]]
//   elems 128..255: Y2XT region, chunk l = [y2[4l..4l+3] | xt[4l..4l+3]]
// e2 lives in a separate dense e2b[N][64] (never gathered).
#define PK_STRIDE 256

__device__ __forceinline__ float4 f4z() { return make_float4(0.f, 0.f, 0.f, 0.f); }
__device__ __forceinline__ void fma4(float4& a, float s, const float4& v) {
  a.x = fmaf(s, v.x, a.x); a.y = fmaf(s, v.y, a.y);
  a.z = fmaf(s, v.z, a.z); a.w = fmaf(s, v.w, a.w);
}
__device__ __forceinline__ float4 add4(const float4& a, const float4& b) {
  return make_float4(a.x + b.x, a.y + b.y, a.z + b.z, a.w + b.w);
}
// lower 4 bf16 of a 16B chunk (elems 0..3)
__device__ __forceinline__ float4 lo4(const uint4& u) {
  float4 f;
  f.x = __uint_as_float(u.x << 16);
  f.y = __uint_as_float(u.x & 0xffff0000u);
  f.z = __uint_as_float(u.y << 16);
  f.w = __uint_as_float(u.y & 0xffff0000u);
  return f;
}
// upper 4 bf16 (elems 4..7)
__device__ __forceinline__ float4 hi4(const uint4& u) {
  float4 f;
  f.x = __uint_as_float(u.z << 16);
  f.y = __uint_as_float(u.z & 0xffff0000u);
  f.z = __uint_as_float(u.w << 16);
  f.w = __uint_as_float(u.w & 0xffff0000u);
  return f;
}
__device__ __forceinline__ float4 ldbf4(const unsigned short* p) {
  ushort4 u = *(const ushort4*)p;
  float4 f;
  f.x = __uint_as_float((unsigned)u.x << 16);
  f.y = __uint_as_float((unsigned)u.y << 16);
  f.z = __uint_as_float((unsigned)u.z << 16);
  f.w = __uint_as_float((unsigned)u.w << 16);
  return f;
}
__device__ __forceinline__ unsigned short f2bf(float v) {
  __hip_bfloat16 h = __float2bfloat16(v);
  return *reinterpret_cast<unsigned short*>(&h);
}
__device__ __forceinline__ unsigned pack2(float a, float b) {
  return ((unsigned)f2bf(b) << 16) | (unsigned)f2bf(a);
}
__device__ __forceinline__ void st4bf(unsigned short* p, const float4& v) {
  ushort4 u;
  u.x = f2bf(v.x); u.y = f2bf(v.y); u.z = f2bf(v.z); u.w = f2bf(v.w);
  *(ushort4*)p = u;
}
__device__ __forceinline__ float fsig(float x) {
  return __builtin_amdgcn_rcpf(1.f + __expf(-x));
}

// -------- init: pk0 E0E1 = [emb0|emb0]; e2b = emb0 --------
__global__ void init_k(const float* __restrict__ emb0, unsigned short* __restrict__ pk0,
                       unsigned short* __restrict__ e2b, int N) {
  int idx = blockIdx.x * blockDim.x + threadIdx.x;
  int n = idx >> 4, q = idx & 15;
  if (n >= N) return;
  float4 v = *(const float4*)(emb0 + (size_t)n * 64 + q * 4);
  unsigned p01 = pack2(v.x, v.y), p23 = pack2(v.z, v.w);
  uint4 u = make_uint4(p01, p23, p01, p23);
  *(uint4*)(pk0 + (size_t)n * PK_STRIDE + q * 8) = u;
  st4bf(e2b + (size_t)n * 64 + q * 4, v);
}

// ---------------- CSR build ----------------
__global__ void hist_k(const int* __restrict__ h, int* __restrict__ deg, int E) {
  int i = blockIdx.x * blockDim.x + threadIdx.x;
  if (i < E) atomicAdd(&deg[h[i]], 1);
}

__global__ void scanA_k(const int* __restrict__ deg, int* __restrict__ rp,
                        int* __restrict__ sums, int N) {
  __shared__ int s[1024];
  int i = blockIdx.x * 1024 + threadIdx.x;
  int v = (i < N) ? deg[i] : 0;
  s[threadIdx.x] = v;
  __syncthreads();
  for (int off = 1; off < 1024; off <<= 1) {
    int t = (threadIdx.x >= (unsigned)off) ? s[threadIdx.x - off] : 0;
    __syncthreads();
    s[threadIdx.x] += t;
    __syncthreads();
  }
  if (i < N) rp[i] = s[threadIdx.x] - v;
  if (threadIdx.x == 1023) sums[blockIdx.x] = s[1023];
}

__global__ void scanB_k(int* sums, int nch) {
  int lane = threadIdx.x;   // 64 threads
  int run = 0;
  for (int base = 0; base < nch; base += 64) {
    int v = (base + lane < nch) ? sums[base + lane] : 0;
    int incl = v;
    for (int off = 1; off < 64; off <<= 1) {
      int t = __shfl_up(incl, off, 64);
      if (lane >= off) incl += t;
    }
    if (base + lane < nch) sums[base + lane] = run + (incl - v);
    run += __shfl(incl, 63, 64);
  }
}

__global__ void scanC_k(int* __restrict__ rp, int* __restrict__ cur,
                        const int* __restrict__ sums, int N, int E) {
  int i = blockIdx.x * blockDim.x + threadIdx.x;
  if (i < N) {
    int v = rp[i] + sums[i >> 10];
    rp[i] = v; cur[i] = v;
  } else if (i == N) {
    rp[N] = E;
  }
}

// fill fused with pregather: write ep (toff, G) and cgum directly at CSR slot
__global__ void fill_k(const int* __restrict__ h, const int* __restrict__ t_idx,
                       const float* __restrict__ G, const float* __restrict__ gum,
                       int* __restrict__ cur, int2* __restrict__ ep,
                       float* __restrict__ cgum, int E, int L) {
  int i = blockIdx.x * blockDim.x + threadIdx.x;
  if (i < E) {
    int pos = atomicAdd(&cur[h[i]], 1);
    ep[pos] = make_int2(t_idx[i] * PK_STRIDE, __float_as_int(G[i]));
    for (int l = 0; l < L; l++) cgum[(size_t)l * E + pos] = gum[(size_t)l * E + i];
  }
}

// ------- degree-balanced row order -------
__device__ __forceinline__ int degbin(int d) { return 63 - min(d, 63); }

__global__ void dhist_k(const int* __restrict__ deg, int* __restrict__ bins, int N) {
  __shared__ int h[64];
  if (threadIdx.x < 64) h[threadIdx.x] = 0;
  __syncthreads();
  int i = blockIdx.x * blockDim.x + threadIdx.x;
  if (i < N) atomicAdd(&h[degbin(deg[i])], 1);
  __syncthreads();
  if (threadIdx.x < 64 && h[threadIdx.x]) atomicAdd(&bins[threadIdx.x], h[threadIdx.x]);
}

__global__ void dscan_k(const int* __restrict__ bins, int* __restrict__ cur2) {
  int lane = threadIdx.x;  // 64
  int v = bins[lane];
  int incl = v;
  for (int off = 1; off < 64; off <<= 1) {
    int t = __shfl_up(incl, off, 64);
    if (lane >= off) incl += t;
  }
  cur2[lane] = incl - v;
}

__global__ void dscatter_k(const int* __restrict__ deg, int* __restrict__ cur2,
                           int* __restrict__ rorder, int N) {
  __shared__ int lcount[64];
  __shared__ int lbase[64];
  if (threadIdx.x < 64) lcount[threadIdx.x] = 0;
  __syncthreads();
  int i = blockIdx.x * blockDim.x + threadIdx.x;
  int bin = 0, lrank = 0;
  bool valid = i < N;
  if (valid) {
    bin = degbin(deg[i]);
    lrank = atomicAdd(&lcount[bin], 1);
  }
  __syncthreads();
  if (threadIdx.x < 64) {
    int c = lcount[threadIdx.x];
    lbase[threadIdx.x] = c ? atomicAdd(&cur2[threadIdx.x], c) : 0;
  }
  __syncthreads();
  if (valid) rorder[lbase[bin] + lrank] = i;
}

// ------- xht: xh -> xhb[N][64] bf16; xt -> Y2XT upper halves -------
__global__ __launch_bounds__(256) void xht_k(const unsigned short* __restrict__ pkin,
                                             const float* __restrict__ W,  // [128][64]
                                             unsigned short* __restrict__ xhb,
                                             unsigned short* __restrict__ pk, int N) {
  __shared__ float et[64 * ST_E];
  __shared__ float wl[64 * ST_WX];
  int tid = threadIdx.x;
  int n0 = blockIdx.x * 64;
  for (int i = tid; i < 64 * 16; i += 256) {
    int r = i >> 4, c = i & 15;
    float4 v = f4z();
    if (n0 + r < N) {
      uint4 u = *(const uint4*)(pkin + (size_t)(n0 + r) * PK_STRIDE + c * 8);
      v = hi4(u);   // e1 quad
    }
    *(float4*)(et + r * ST_E + c * 4) = v;
  }
  for (int i = tid; i < 128 * 16; i += 256) {
    int r = i >> 4, c4 = (i & 15) * 4;
    float4 v = *(const float4*)(W + r * 64 + c4);
    if (r < 64) *(float4*)(wl + r * ST_WX + c4) = v;
    else        *(float4*)(wl + (r - 64) * ST_WX + 64 + c4) = v;
  }
  __syncthreads();
  int rg = tid >> 4, tx = tid & 15;
  int s2 = (tx >> 2) * 2;
  float acc[4][8];
#pragma unroll
  for (int i = 0; i < 4; i++)
#pragma unroll
    for (int j = 0; j < 8; j++) acc[i][j] = 0.f;
#pragma unroll 4
  for (int k = 0; k < 64; k++) {
    int kk = (k + s2) & 63;
    float a0 = et[(rg * 4 + 0) * ST_E + kk];
    float a1 = et[(rg * 4 + 1) * ST_E + kk];
    float a2 = et[(rg * 4 + 2) * ST_E + kk];
    float a3 = et[(rg * 4 + 3) * ST_E + kk];
    float4 b0 = *(const float4*)(wl + kk * ST_WX + tx * 4);        // xh cols tx*4
    float4 b1 = *(const float4*)(wl + kk * ST_WX + 64 + tx * 4);   // xt cols tx*4
    acc[0][0] = fmaf(a0, b0.x, acc[0][0]); acc[0][1] = fmaf(a0, b0.y, acc[0][1]);
    acc[0][2] = fmaf(a0, b0.z, acc[0][2]); acc[0][3] = fmaf(a0, b0.w, acc[0][3]);
    acc[0][4] = fmaf(a0, b1.x, acc[0][4]); acc[0][5] = fmaf(a0, b1.y, acc[0][5]);
    acc[0][6] = fmaf(a0, b1.z, acc[0][6]); acc[0][7] = fmaf(a0, b1.w, acc[0][7]);
    acc[1][0] = fmaf(a1, b0.x, acc[1][0]); acc[1][1] = fmaf(a1, b0.y, acc[1][1]);
    acc[1][2] = fmaf(a1, b0.z, acc[1][2]); acc[1][3] = fmaf(a1, b0.w, acc[1][3]);
    acc[1][4] = fmaf(a1, b1.x, acc[1][4]); acc[1][5] = fmaf(a1, b1.y, acc[1][5]);
    acc[1][6] = fmaf(a1, b1.z, acc[1][6]); acc[1][7] = fmaf(a1, b1.w, acc[1][7]);
    acc[2][0] = fmaf(a2, b0.x, acc[2][0]); acc[2][1] = fmaf(a2, b0.y, acc[2][1]);
    acc[2][2] = fmaf(a2, b0.z, acc[2][2]); acc[2][3] = fmaf(a2, b0.w, acc[2][3]);
    acc[2][4] = fmaf(a2, b1.x, acc[2][4]); acc[2][5] = fmaf(a2, b1.y, acc[2][5]);
    acc[2][6] = fmaf(a2, b1.z, acc[2][6]); acc[2][7] = fmaf(a2, b1.w, acc[2][7]);
    acc[3][0] = fmaf(a3, b0.x, acc[3][0]); acc[3][1] = fmaf(a3, b0.y, acc[3][1]);
    acc[3][2] = fmaf(a3, b0.z, acc[3][2]); acc[3][3] = fmaf(a3, b0.w, acc[3][3]);
    acc[3][4] = fmaf(a3, b1.x, acc[3][4]); acc[3][5] = fmaf(a3, b1.y, acc[3][5]);
    acc[3][6] = fmaf(a3, b1.z, acc[3][6]); acc[3][7] = fmaf(a3, b1.w, acc[3][7]);
  }
#pragma unroll
  for (int i = 0; i < 4; i++) {
    int n = n0 + rg * 4 + i;
    if (n < N) {
      st4bf(xhb + (size_t)n * 64 + tx * 4,
            make_float4(acc[i][0], acc[i][1], acc[i][2], acc[i][3]));
      st4bf(pk + (size_t)n * PK_STRIDE + 128 + tx * 8 + 4,
            make_float4(acc[i][4], acc[i][5], acc[i][6], acc[i][7]));
    }
  }
}

// ------- node MLP + gate: y2 -> Y2XT lower halves (reads e2b) -------
__global__ __launch_bounds__(256) void mlp2_k(const unsigned short* __restrict__ e2b,
    const float* __restrict__ W1, const float* __restrict__ b1,
    const float* __restrict__ W2, const float* __restrict__ b2,
    const float* __restrict__ gum, unsigned short* __restrict__ pk, int N) {
  __shared__ float et[64 * ST_E];
  __shared__ float w1l[64 * ST_W];
  __shared__ float w2l[64 * ST_W];
  __shared__ float ht[64 * ST_E];
  int tid = threadIdx.x;
  int n0 = blockIdx.x * 64;
  for (int i = tid; i < 64 * 16; i += 256) {
    int r = i >> 4, c4 = (i & 15) * 4;
    float4 v = (n0 + r < N) ? ldbf4(e2b + (size_t)(n0 + r) * 64 + c4) : f4z();
    *(float4*)(et + r * ST_E + c4) = v;
    *(float4*)(w1l + r * ST_W + c4) = *(const float4*)(W1 + r * 64 + c4);
    *(float4*)(w2l + r * ST_W + c4) = *(const float4*)(W2 + r * 64 + c4);
  }
  __syncthreads();
  int rg = tid >> 4, tx = tid & 15;
  int s2 = (tx >> 2) * 2;
  float acc[4][4];
#pragma unroll
  for (int i = 0; i < 4; i++)
#pragma unroll
    for (int j = 0; j < 4; j++) acc[i][j] = 0.f;
#pragma unroll 4
  for (int k = 0; k < 64; k++) {
    int kk = (k + s2) & 63;
    float a0 = et[(rg * 4 + 0) * ST_E + kk];
    float a1 = et[(rg * 4 + 1) * ST_E + kk];
    float a2 = et[(rg * 4 + 2) * ST_E + kk];
    float a3 = et[(rg * 4 + 3) * ST_E + kk];
    float4 bv = *(const float4*)(w1l + kk * ST_W + tx * 4);
    acc[0][0] = fmaf(a0, bv.x, acc[0][0]); acc[0][1] = fmaf(a0, bv.y, acc[0][1]);
    acc[0][2] = fmaf(a0, bv.z, acc[0][2]); acc[0][3] = fmaf(a0, bv.w, acc[0][3]);
    acc[1][0] = fmaf(a1, bv.x, acc[1][0]); acc[1][1] = fmaf(a1, bv.y, acc[1][1]);
    acc[1][2] = fmaf(a1, bv.z, acc[1][2]); acc[1][3] = fmaf(a1, bv.w, acc[1][3]);
    acc[2][0] = fmaf(a2, bv.x, acc[2][0]); acc[2][1] = fmaf(a2, bv.y, acc[2][1]);
    acc[2][2] = fmaf(a2, bv.z, acc[2][2]); acc[2][3] = fmaf(a2, bv.w, acc[2][3]);
    acc[3][0] = fmaf(a3, bv.x, acc[3][0]); acc[3][1] = fmaf(a3, bv.y, acc[3][1]);
    acc[3][2] = fmaf(a3, bv.z, acc[3][2]); acc[3][3] = fmaf(a3, bv.w, acc[3][3]);
  }
  float4 b1v = *(const float4*)(b1 + tx * 4);
#pragma unroll
  for (int i = 0; i < 4; i++) {
    float4 hv = make_float4(fmaxf(acc[i][0] + b1v.x, 0.f), fmaxf(acc[i][1] + b1v.y, 0.f),
                            fmaxf(acc[i][2] + b1v.z, 0.f), fmaxf(acc[i][3] + b1v.w, 0.f));
    *(float4*)(ht + (rg * 4 + i) * ST_E + tx * 4) = hv;
  }
  __syncthreads();
  float acc2[4][4];
#pragma unroll
  for (int i = 0; i < 4; i++)
#pragma unroll
    for (int j = 0; j < 4; j++) acc2[i][j] = 0.f;
#pragma unroll 4
  for (int k = 0; k < 64; k++) {
    int kk = (k + s2) & 63;
    float a0 = ht[(rg * 4 + 0) * ST_E + kk];
    float a1 = ht[(rg * 4 + 1) * ST_E + kk];
    float a2 = ht[(rg * 4 + 2) * ST_E + kk];
    float a3 = ht[(rg * 4 + 3) * ST_E + kk];
    float4 bv = *(const float4*)(w2l + kk * ST_W + tx * 4);
    acc2[0][0] = fmaf(a0, bv.x, acc2[0][0]); acc2[0][1] = fmaf(a0, bv.y, acc2[0][1]);
    acc2[0][2] = fmaf(a0, bv.z, acc2[0][2]); acc2[0][3] = fmaf(a0, bv.w, acc2[0][3]);
    acc2[1][0] = fmaf(a1, bv.x, acc2[1][0]); acc2[1][1] = fmaf(a1, bv.y, acc2[1][1]);
    acc2[1][2] = fmaf(a1, bv.z, acc2[1][2]); acc2[1][3] = fmaf(a1, bv.w, acc2[1][3]);
    acc2[2][0] = fmaf(a2, bv.x, acc2[2][0]); acc2[2][1] = fmaf(a2, bv.y, acc2[2][1]);
    acc2[2][2] = fmaf(a2, bv.z, acc2[2][2]); acc2[2][3] = fmaf(a2, bv.w, acc2[2][3]);
    acc2[3][0] = fmaf(a3, bv.x, acc2[3][0]); acc2[3][1] = fmaf(a3, bv.y, acc2[3][1]);
    acc2[3][2] = fmaf(a3, bv.z, acc2[3][2]); acc2[3][3] = fmaf(a3, bv.w, acc2[3][3]);
  }
  float4 b2v = *(const float4*)(b2 + tx * 4);
#pragma unroll
  for (int i = 0; i < 4; i++) {
    int n = n0 + rg * 4 + i;
    if (n < N) {
      float4 gv = *(const float4*)(gum + (size_t)n * 64 + tx * 4);
      float4 ev = *(const float4*)(et + (rg * 4 + i) * ST_E + tx * 4);
      float4 yv;
      yv.x = ev.x * fsig(gv.x + acc2[i][0] + b2v.x);
      yv.y = ev.y * fsig(gv.y + acc2[i][1] + b2v.y);
      yv.z = ev.z * fsig(gv.z + acc2[i][2] + b2v.z);
      yv.w = ev.w * fsig(gv.w + acc2[i][3] + b2v.w);
      st4bf(pk + (size_t)n * PK_STRIDE + 128 + tx * 8, yv);
    }
  }
}

// ------- fused 3-branch SpMM + edge-MLP + dinv + residual + out -------
#define CH 4

#define LOADCH(Abuf, Bbuf, I0)                                          \
  _Pragma("unroll")                                                     \
  for (int c = 0; c < CH; c++) {                                        \
    int i_ = (I0) + c;                                                  \
    int tof_ = __shfl(ev.x, i_ & 15, 16);                               \
    if (i_ < cnt) {                                                     \
      const unsigned short* pr_ = pk + (size_t)tof_ + l * 8;            \
      Abuf[c] = *(const uint4*)(pr_);                                   \
      Bbuf[c] = *(const uint4*)(pr_ + 128);                             \
    }                                                                   \
  }

#define COMPCH(Abuf, Bbuf, I0)                                          \
  _Pragma("unroll")                                                     \
  for (int c = 0; c < CH; c++) {                                        \
    int i_ = (I0) + c;                                                  \
    float gg_ = __shfl(__int_as_float(ev.y), i_ & 15, 16);              \
    float gu_ = __shfl(guv, i_ & 15, 16);                               \
    if (i_ < cnt) {                                                     \
      float4 v0_ = lo4(Abuf[c]);                                        \
      float4 v1_ = hi4(Abuf[c]);                                        \
      float4 vy_ = lo4(Bbuf[c]);                                        \
      float4 xt_ = hi4(Bbuf[c]);                                        \
      float pq_ = fmaxf(xb1.x + xt_.x, 0.f) * w2v.x                     \
                + fmaxf(xb1.y + xt_.y, 0.f) * w2v.y                     \
                + fmaxf(xb1.z + xt_.z, 0.f) * w2v.z                     \
                + fmaxf(xb1.w + xt_.w, 0.f) * w2v.w;                    \
      pq_ += __shfl_xor(pq_, 1, 16);                                    \
      pq_ += __shfl_xor(pq_, 2, 16);                                    \
      pq_ += __shfl_xor(pq_, 4, 16);                                    \
      pq_ += __shfl_xor(pq_, 8, 16);                                    \
      float w_ = fsig(gu_ + pq_ + b2s);                                 \
      wsum += w_;                                                       \
      fma4(acc0, gg_, v0_);                                             \
      fma4(acc1, w_, v1_);                                              \
      fma4(acc2, gg_, vy_);                                             \
    }                                                                   \
  }

// OUTM: 0 = no out;  1 = out = emb0 + rc + en (L=2 final);
//       2 = out = rc + en; 3 = out += en
template <int FIRST, int OUTM>
__global__ __launch_bounds__(256) void spmm3f_k(const int* __restrict__ rp,
    const int* __restrict__ rorder,
    const int2* __restrict__ ep, const float* __restrict__ cgum,
    const unsigned short* __restrict__ pk, const unsigned short* __restrict__ xhb,
    const unsigned short* __restrict__ e2b_in,
    const float* __restrict__ b1, const float* __restrict__ W2,
    const float* __restrict__ b2, const float* __restrict__ emb0,
    unsigned short* __restrict__ pkn, unsigned short* __restrict__ e2b,
    float* __restrict__ out0, float* __restrict__ out1, float* __restrict__ out2,
    int N) {
  int g = threadIdx.x >> 4;
  int l = threadIdx.x & 15;
  int gid = blockIdx.x * 16 + g;
  if (gid >= N) return;
  int n = rorder[gid];
  int jb = rp[n], je = rp[n + 1];
  size_t o64 = (size_t)n * 64 + l * 4;
  float4 xh4 = ldbf4(xhb + o64);
  float4 b1v = *(const float4*)(b1 + l * 4);
  float4 xb1 = add4(xh4, b1v);
  float4 w2v = *(const float4*)(W2 + l * 4);
  float b2s = b2[0];
  float4 rc0, rc1, rc2;
  if (FIRST) {
    rc0 = *(const float4*)(emb0 + o64);
    rc1 = rc0; rc2 = rc0;
  } else {
    uint4 rA = *(const uint4*)(pk + (size_t)n * PK_STRIDE + l * 8);
    rc0 = lo4(rA);
    rc1 = hi4(rA);
    rc2 = ldbf4(e2b_in + o64);
  }
  float4 acc0 = f4z(), acc1 = f4z(), acc2 = f4z();
  float wsum = 0.f;
  for (int base = jb; base < je; base += 16) {
    int idx = base + l;
    bool valid = idx < je;
    int2 ev = valid ? ep[idx] : make_int2(0, 0);
    float guv = valid ? cgum[idx] : 0.f;
    int cnt = min(16, je - base);
    uint4 A0[CH], B0[CH], A1[CH], B1[CH];
    LOADCH(A0, B0, 0)
    for (int i0 = 0; i0 < cnt; i0 += 2 * CH) {
      LOADCH(A1, B1, i0 + CH)
      COMPCH(A0, B0, i0)
      LOADCH(A0, B0, i0 + 2 * CH)
      COMPCH(A1, B1, i0 + CH)
    }
  }
  float dinv = (wsum > 0.f) ? __builtin_amdgcn_rcpf(wsum) : 0.f;
  float4 en0 = add4(acc0, rc0);
  acc1.x *= dinv; acc1.y *= dinv; acc1.z *= dinv; acc1.w *= dinv;
  float4 en1 = add4(acc1, rc1);
  float4 en2 = add4(acc2, rc2);
  uint4 wA;
  wA.x = pack2(en0.x, en0.y); wA.y = pack2(en0.z, en0.w);
  wA.z = pack2(en1.x, en1.y); wA.w = pack2(en1.z, en1.w);
  *(uint4*)(pkn + (size_t)n * PK_STRIDE + l * 8) = wA;
  st4bf(e2b + o64, en2);
  if (OUTM == 1) {
    float4 base = *(const float4*)(emb0 + o64);
    *(float4*)(out0 + o64) = add4(base, add4(rc0, en0));
    *(float4*)(out1 + o64) = add4(base, add4(rc1, en1));
    *(float4*)(out2 + o64) = add4(base, add4(rc2, en2));
  } else if (OUTM == 2) {
    *(float4*)(out0 + o64) = add4(rc0, en0);
    *(float4*)(out1 + o64) = add4(rc1, en1);
    *(float4*)(out2 + o64) = add4(rc2, en2);
  } else if (OUTM == 3) {
    *(float4*)(out0 + o64) = add4(*(const float4*)(out0 + o64), en0);
    *(float4*)(out1 + o64) = add4(*(const float4*)(out1 + o64), en1);
    *(float4*)(out2 + o64) = add4(*(const float4*)(out2 + o64), en2);
  }
}

extern "C" void kernel_launch(void* const* d_in, const int* in_sizes, int n_in,
                              void* d_out, int out_size, void* d_ws, size_t ws_size,
                              hipStream_t stream) {
  const float* emb0        = (const float*)d_in[0];
  const int*   h_idx       = (const int*)d_in[1];
  const int*   t_idx       = (const int*)d_in[2];
  const float* G_values    = (const float*)d_in[3];
  const float* edge_gumbel = (const float*)d_in[4];
  const float* emb_gumbel  = (const float*)d_in[5];
  const float* edge_W1     = (const float*)d_in[6];
  const float* edge_b1     = (const float*)d_in[7];
  const float* edge_W2     = (const float*)d_in[8];
  const float* edge_b2     = (const float*)d_in[9];
  const float* emb_W1      = (const float*)d_in[10];
  const float* emb_b1      = (const float*)d_in[11];
  const float* emb_W2      = (const float*)d_in[12];
  const float* emb_b2      = (const float*)d_in[13];

  const int D = 64;
  const int N = in_sizes[0] / D;
  const int E = in_sizes[1];
  const int L = in_sizes[4] / E;
  const size_t ND = (size_t)N * D;

  char* p = (char*)d_ws;
  auto alloc = [&](size_t bytes) -> char* {
    char* r = p;
    p += (bytes + 255) & ~(size_t)255;
    return r;
  };
  unsigned short* xhb = (unsigned short*)alloc(ND * 2);
  unsigned short* e2b = (unsigned short*)alloc(ND * 2);
  unsigned short* pkA = (unsigned short*)alloc((size_t)N * PK_STRIDE * 2);
  unsigned short* pkB = (unsigned short*)alloc((size_t)N * PK_STRIDE * 2);
  int2*  ep    = (int2*)alloc((size_t)E * 8);
  float* cgum  = (float*)alloc((size_t)L * E * 4);
  int*   deg   = (int*)alloc(((size_t)N + 128) * 4);   // deg[N] | bins[64] | cur2[64]
  int*   bins  = deg + N;
  int*   cur2  = deg + N + 64;
  int*   cur   = (int*)alloc((size_t)N * 4);
  int*   rp    = (int*)alloc(((size_t)N + 1) * 4);
  int*   rorder = (int*)alloc((size_t)N * 4);
  int*   sums  = (int*)alloc(1024 * 4);

  float* out = (float*)d_out;

  init_k<<<(N * 16 + 255) / 256, 256, 0, stream>>>(emb0, pkA, e2b, N);
  hipMemsetAsync(deg, 0, ((size_t)N + 128) * 4, stream);
  hist_k<<<(E + 255) / 256, 256, 0, stream>>>(h_idx, deg, E);
  int nch = (N + 1023) / 1024;
  scanA_k<<<nch, 1024, 0, stream>>>(deg, rp, sums, N);
  scanB_k<<<1, 64, 0, stream>>>(sums, nch);
  scanC_k<<<(N + 256) / 256, 256, 0, stream>>>(rp, cur, sums, N, E);
  fill_k<<<(E + 255) / 256, 256, 0, stream>>>(h_idx, t_idx, G_values, edge_gumbel,
                                              cur, ep, cgum, E, L);
  dhist_k<<<(N + 255) / 256, 256, 0, stream>>>(deg, bins, N);
  dscan_k<<<1, 64, 0, stream>>>(bins, cur2);
  dscatter_k<<<(N + 255) / 256, 256, 0, stream>>>(deg, cur2, rorder, N);

  int nb64 = (N + 63) / 64;
  int nb16 = (N + 15) / 16;

  for (int i = 0; i < L; i++) {
    unsigned short* pkc = (i & 1) ? pkB : pkA;
    unsigned short* pkn = (i & 1) ? pkA : pkB;
    xht_k<<<nb64, 256, 0, stream>>>(pkc, edge_W1 + (size_t)i * 128 * 64, xhb, pkc, N);
    mlp2_k<<<nb64, 256, 0, stream>>>(e2b, emb_W1 + (size_t)i * 4096,
                                     emb_b1 + (size_t)i * 64,
                                     emb_W2 + (size_t)i * 4096,
                                     emb_b2 + (size_t)i * 64,
                                     emb_gumbel + (size_t)i * ND, pkc, N);
    const float* cg = cgum + (size_t)i * E;
    const float* eb1 = edge_b1 + (size_t)i * 64;
    const float* eW2 = edge_W2 + (size_t)i * 64;
    const float* eb2 = edge_b2 + i;
    if (L == 2) {
      if (i == 0)
        spmm3f_k<1, 0><<<nb16, 256, 0, stream>>>(rp, rorder, ep, cg, pkc, xhb, e2b,
                                                 eb1, eW2, eb2, emb0, pkn, e2b,
                                                 out, out + ND, out + 2 * ND, N);
      else
        spmm3f_k<0, 1><<<nb16, 256, 0, stream>>>(rp, rorder, ep, cg, pkc, xhb, e2b,
                                                 eb1, eW2, eb2, emb0, pkn, e2b,
                                                 out, out + ND, out + 2 * ND, N);
    } else {
      if (i == 0)
        spmm3f_k<1, 2><<<nb16, 256, 0, stream>>>(rp, rorder, ep, cg, pkc, xhb, e2b,
                                                 eb1, eW2, eb2, emb0, pkn, e2b,
                                                 out, out + ND, out + 2 * ND, N);
      else
        spmm3f_k<0, 3><<<nb16, 256, 0, stream>>>(rp, rorder, ep, cg, pkc, xhb, e2b,
                                                 eb1, eW2, eb2, emb0, pkn, e2b,
                                                 out, out + ND, out + 2 * ND, N);
    }
  }
}

// Round 8
// 410.003 us; speedup vs baseline: 1.9994x; 1.1511x over previous
//
#include <hip/hip_runtime.h>
#include <hip/hip_bf16.h>
#include <math.h>

#define ST_E 68
#define ST_W 68
#define ST_WX 132

// pk row: 256 bf16 = 512B, line-aligned.
//   elems 0..127  : E0E1 region, chunk l (l=0..15) = [e0[4l..4l+3] | e1[4l..4l+3]]
//   elems 128..255: Y2XT region, chunk l = [y2[4l..4l+3] | xt[4l..4l+3]]
// e2 lives in a separate dense e2b[N][64] (never gathered).
#define PK_STRIDE 256

typedef float v4f __attribute__((ext_vector_type(4)));

__device__ __forceinline__ float4 f4z() { return make_float4(0.f, 0.f, 0.f, 0.f); }
__device__ __forceinline__ void fma4(float4& a, float s, const float4& v) {
  a.x = fmaf(s, v.x, a.x); a.y = fmaf(s, v.y, a.y);
  a.z = fmaf(s, v.z, a.z); a.w = fmaf(s, v.w, a.w);
}
__device__ __forceinline__ float4 add4(const float4& a, const float4& b) {
  return make_float4(a.x + b.x, a.y + b.y, a.z + b.z, a.w + b.w);
}
__device__ __forceinline__ void stnt4(float* p, const float4& v) {
  v4f u; u.x = v.x; u.y = v.y; u.z = v.z; u.w = v.w;
  __builtin_nontemporal_store(u, (v4f*)p);
}
// lower 4 bf16 of a 16B chunk (elems 0..3)
__device__ __forceinline__ float4 lo4(const uint4& u) {
  float4 f;
  f.x = __uint_as_float(u.x << 16);
  f.y = __uint_as_float(u.x & 0xffff0000u);
  f.z = __uint_as_float(u.y << 16);
  f.w = __uint_as_float(u.y & 0xffff0000u);
  return f;
}
// upper 4 bf16 (elems 4..7)
__device__ __forceinline__ float4 hi4(const uint4& u) {
  float4 f;
  f.x = __uint_as_float(u.z << 16);
  f.y = __uint_as_float(u.z & 0xffff0000u);
  f.z = __uint_as_float(u.w << 16);
  f.w = __uint_as_float(u.w & 0xffff0000u);
  return f;
}
__device__ __forceinline__ float4 ldbf4(const unsigned short* p) {
  ushort4 u = *(const ushort4*)p;
  float4 f;
  f.x = __uint_as_float((unsigned)u.x << 16);
  f.y = __uint_as_float((unsigned)u.y << 16);
  f.z = __uint_as_float((unsigned)u.z << 16);
  f.w = __uint_as_float((unsigned)u.w << 16);
  return f;
}
__device__ __forceinline__ unsigned short f2bf(float v) {
  __hip_bfloat16 h = __float2bfloat16(v);
  return *reinterpret_cast<unsigned short*>(&h);
}
__device__ __forceinline__ unsigned pack2(float a, float b) {
  return ((unsigned)f2bf(b) << 16) | (unsigned)f2bf(a);
}
__device__ __forceinline__ void st4bf(unsigned short* p, const float4& v) {
  ushort4 u;
  u.x = f2bf(v.x); u.y = f2bf(v.y); u.z = f2bf(v.z); u.w = f2bf(v.w);
  *(ushort4*)p = u;
}
__device__ __forceinline__ float fsig(float x) {
  return __builtin_amdgcn_rcpf(1.f + __expf(-x));
}

// -------- init: pk0 E0E1 = [emb0|emb0]; e2b = emb0 --------
__global__ void init_k(const float* __restrict__ emb0, unsigned short* __restrict__ pk0,
                       unsigned short* __restrict__ e2b, int N) {
  int idx = blockIdx.x * blockDim.x + threadIdx.x;
  int n = idx >> 4, q = idx & 15;
  if (n >= N) return;
  float4 v = *(const float4*)(emb0 + (size_t)n * 64 + q * 4);
  unsigned p01 = pack2(v.x, v.y), p23 = pack2(v.z, v.w);
  uint4 u = make_uint4(p01, p23, p01, p23);
  *(uint4*)(pk0 + (size_t)n * PK_STRIDE + q * 8) = u;
  st4bf(e2b + (size_t)n * 64 + q * 4, v);
}

// ---------------- CSR build ----------------
__global__ void hist_k(const int* __restrict__ h, int* __restrict__ deg, int E) {
  int i = blockIdx.x * blockDim.x + threadIdx.x;
  if (i < E) atomicAdd(&deg[h[i]], 1);
}

__global__ void scanA_k(const int* __restrict__ deg, int* __restrict__ rp,
                        int* __restrict__ sums, int N) {
  __shared__ int s[1024];
  int i = blockIdx.x * 1024 + threadIdx.x;
  int v = (i < N) ? deg[i] : 0;
  s[threadIdx.x] = v;
  __syncthreads();
  for (int off = 1; off < 1024; off <<= 1) {
    int t = (threadIdx.x >= (unsigned)off) ? s[threadIdx.x - off] : 0;
    __syncthreads();
    s[threadIdx.x] += t;
    __syncthreads();
  }
  if (i < N) rp[i] = s[threadIdx.x] - v;
  if (threadIdx.x == 1023) sums[blockIdx.x] = s[1023];
}

__global__ void scanB_k(int* sums, int nch) {
  int lane = threadIdx.x;   // 64 threads
  int run = 0;
  for (int base = 0; base < nch; base += 64) {
    int v = (base + lane < nch) ? sums[base + lane] : 0;
    int incl = v;
    for (int off = 1; off < 64; off <<= 1) {
      int t = __shfl_up(incl, off, 64);
      if (lane >= off) incl += t;
    }
    if (base + lane < nch) sums[base + lane] = run + (incl - v);
    run += __shfl(incl, 63, 64);
  }
}

__global__ void scanC_k(int* __restrict__ rp, int* __restrict__ cur,
                        const int* __restrict__ sums, int N, int E) {
  int i = blockIdx.x * blockDim.x + threadIdx.x;
  if (i < N) {
    int v = rp[i] + sums[i >> 10];
    rp[i] = v; cur[i] = v;
  } else if (i == N) {
    rp[N] = E;
  }
}

// fill: one 16B emeta write per edge {toff, G, gum_l0, gum_l1}; cgum only if L>2
__global__ void fill_k(const int* __restrict__ h, const int* __restrict__ t_idx,
                       const float* __restrict__ G, const float* __restrict__ gum,
                       int* __restrict__ cur, int4* __restrict__ emeta,
                       float* __restrict__ cgum, int E, int L) {
  int i = blockIdx.x * blockDim.x + threadIdx.x;
  if (i < E) {
    int pos = atomicAdd(&cur[h[i]], 1);
    int4 em;
    em.x = t_idx[i] * PK_STRIDE;
    em.y = __float_as_int(G[i]);
    em.z = __float_as_int(gum[i]);
    em.w = (L > 1) ? __float_as_int(gum[(size_t)E + i]) : 0;
    emeta[pos] = em;
    if (L > 2)
      for (int l = 2; l < L; l++) cgum[(size_t)l * E + pos] = gum[(size_t)l * E + i];
  }
}

// ------- xht: xh -> xhb[N][64] bf16; xt -> Y2XT upper halves -------
__global__ __launch_bounds__(256) void xht_k(const unsigned short* __restrict__ pkin,
                                             const float* __restrict__ W,  // [128][64]
                                             unsigned short* __restrict__ xhb,
                                             unsigned short* __restrict__ pk, int N) {
  __shared__ float et[64 * ST_E];
  __shared__ float wl[64 * ST_WX];
  int tid = threadIdx.x;
  int n0 = blockIdx.x * 64;
  for (int i = tid; i < 64 * 16; i += 256) {
    int r = i >> 4, c = i & 15;
    float4 v = f4z();
    if (n0 + r < N) {
      uint4 u = *(const uint4*)(pkin + (size_t)(n0 + r) * PK_STRIDE + c * 8);
      v = hi4(u);   // e1 quad
    }
    *(float4*)(et + r * ST_E + c * 4) = v;
  }
  for (int i = tid; i < 128 * 16; i += 256) {
    int r = i >> 4, c4 = (i & 15) * 4;
    float4 v = *(const float4*)(W + r * 64 + c4);
    if (r < 64) *(float4*)(wl + r * ST_WX + c4) = v;
    else        *(float4*)(wl + (r - 64) * ST_WX + 64 + c4) = v;
  }
  __syncthreads();
  int rg = tid >> 4, tx = tid & 15;
  int s2 = (tx >> 2) * 2;
  float acc[4][8];
#pragma unroll
  for (int i = 0; i < 4; i++)
#pragma unroll
    for (int j = 0; j < 8; j++) acc[i][j] = 0.f;
#pragma unroll 4
  for (int k = 0; k < 64; k++) {
    int kk = (k + s2) & 63;
    float a0 = et[(rg * 4 + 0) * ST_E + kk];
    float a1 = et[(rg * 4 + 1) * ST_E + kk];
    float a2 = et[(rg * 4 + 2) * ST_E + kk];
    float a3 = et[(rg * 4 + 3) * ST_E + kk];
    float4 b0 = *(const float4*)(wl + kk * ST_WX + tx * 4);        // xh cols
    float4 b1 = *(const float4*)(wl + kk * ST_WX + 64 + tx * 4);   // xt cols
    acc[0][0] = fmaf(a0, b0.x, acc[0][0]); acc[0][1] = fmaf(a0, b0.y, acc[0][1]);
    acc[0][2] = fmaf(a0, b0.z, acc[0][2]); acc[0][3] = fmaf(a0, b0.w, acc[0][3]);
    acc[0][4] = fmaf(a0, b1.x, acc[0][4]); acc[0][5] = fmaf(a0, b1.y, acc[0][5]);
    acc[0][6] = fmaf(a0, b1.z, acc[0][6]); acc[0][7] = fmaf(a0, b1.w, acc[0][7]);
    acc[1][0] = fmaf(a1, b0.x, acc[1][0]); acc[1][1] = fmaf(a1, b0.y, acc[1][1]);
    acc[1][2] = fmaf(a1, b0.z, acc[1][2]); acc[1][3] = fmaf(a1, b0.w, acc[1][3]);
    acc[1][4] = fmaf(a1, b1.x, acc[1][4]); acc[1][5] = fmaf(a1, b1.y, acc[1][5]);
    acc[1][6] = fmaf(a1, b1.z, acc[1][6]); acc[1][7] = fmaf(a1, b1.w, acc[1][7]);
    acc[2][0] = fmaf(a2, b0.x, acc[2][0]); acc[2][1] = fmaf(a2, b0.y, acc[2][1]);
    acc[2][2] = fmaf(a2, b0.z, acc[2][2]); acc[2][3] = fmaf(a2, b0.w, acc[2][3]);
    acc[2][4] = fmaf(a2, b1.x, acc[2][4]); acc[2][5] = fmaf(a2, b1.y, acc[2][5]);
    acc[2][6] = fmaf(a2, b1.z, acc[2][6]); acc[2][7] = fmaf(a2, b1.w, acc[2][7]);
    acc[3][0] = fmaf(a3, b0.x, acc[3][0]); acc[3][1] = fmaf(a3, b0.y, acc[3][1]);
    acc[3][2] = fmaf(a3, b0.z, acc[3][2]); acc[3][3] = fmaf(a3, b0.w, acc[3][3]);
    acc[3][4] = fmaf(a3, b1.x, acc[3][4]); acc[3][5] = fmaf(a3, b1.y, acc[3][5]);
    acc[3][6] = fmaf(a3, b1.z, acc[3][6]); acc[3][7] = fmaf(a3, b1.w, acc[3][7]);
  }
#pragma unroll
  for (int i = 0; i < 4; i++) {
    int n = n0 + rg * 4 + i;
    if (n < N) {
      st4bf(xhb + (size_t)n * 64 + tx * 4,
            make_float4(acc[i][0], acc[i][1], acc[i][2], acc[i][3]));
      st4bf(pk + (size_t)n * PK_STRIDE + 128 + tx * 8 + 4,
            make_float4(acc[i][4], acc[i][5], acc[i][6], acc[i][7]));
    }
  }
}

// ------- node MLP + gate: y2 -> Y2XT lower halves (reads e2b) -------
__global__ __launch_bounds__(256) void mlp2_k(const unsigned short* __restrict__ e2b,
    const float* __restrict__ W1, const float* __restrict__ b1,
    const float* __restrict__ W2, const float* __restrict__ b2,
    const float* __restrict__ gum, unsigned short* __restrict__ pk, int N) {
  __shared__ float et[64 * ST_E];
  __shared__ float w1l[64 * ST_W];
  __shared__ float w2l[64 * ST_W];
  __shared__ float ht[64 * ST_E];
  int tid = threadIdx.x;
  int n0 = blockIdx.x * 64;
  for (int i = tid; i < 64 * 16; i += 256) {
    int r = i >> 4, c4 = (i & 15) * 4;
    float4 v = (n0 + r < N) ? ldbf4(e2b + (size_t)(n0 + r) * 64 + c4) : f4z();
    *(float4*)(et + r * ST_E + c4) = v;
    *(float4*)(w1l + r * ST_W + c4) = *(const float4*)(W1 + r * 64 + c4);
    *(float4*)(w2l + r * ST_W + c4) = *(const float4*)(W2 + r * 64 + c4);
  }
  __syncthreads();
  int rg = tid >> 4, tx = tid & 15;
  int s2 = (tx >> 2) * 2;
  float acc[4][4];
#pragma unroll
  for (int i = 0; i < 4; i++)
#pragma unroll
    for (int j = 0; j < 4; j++) acc[i][j] = 0.f;
#pragma unroll 4
  for (int k = 0; k < 64; k++) {
    int kk = (k + s2) & 63;
    float a0 = et[(rg * 4 + 0) * ST_E + kk];
    float a1 = et[(rg * 4 + 1) * ST_E + kk];
    float a2 = et[(rg * 4 + 2) * ST_E + kk];
    float a3 = et[(rg * 4 + 3) * ST_E + kk];
    float4 bv = *(const float4*)(w1l + kk * ST_W + tx * 4);
    acc[0][0] = fmaf(a0, bv.x, acc[0][0]); acc[0][1] = fmaf(a0, bv.y, acc[0][1]);
    acc[0][2] = fmaf(a0, bv.z, acc[0][2]); acc[0][3] = fmaf(a0, bv.w, acc[0][3]);
    acc[1][0] = fmaf(a1, bv.x, acc[1][0]); acc[1][1] = fmaf(a1, bv.y, acc[1][1]);
    acc[1][2] = fmaf(a1, bv.z, acc[1][2]); acc[1][3] = fmaf(a1, bv.w, acc[1][3]);
    acc[2][0] = fmaf(a2, bv.x, acc[2][0]); acc[2][1] = fmaf(a2, bv.y, acc[2][1]);
    acc[2][2] = fmaf(a2, bv.z, acc[2][2]); acc[2][3] = fmaf(a2, bv.w, acc[2][3]);
    acc[3][0] = fmaf(a3, bv.x, acc[3][0]); acc[3][1] = fmaf(a3, bv.y, acc[3][1]);
    acc[3][2] = fmaf(a3, bv.z, acc[3][2]); acc[3][3] = fmaf(a3, bv.w, acc[3][3]);
  }
  float4 b1v = *(const float4*)(b1 + tx * 4);
#pragma unroll
  for (int i = 0; i < 4; i++) {
    float4 hv = make_float4(fmaxf(acc[i][0] + b1v.x, 0.f), fmaxf(acc[i][1] + b1v.y, 0.f),
                            fmaxf(acc[i][2] + b1v.z, 0.f), fmaxf(acc[i][3] + b1v.w, 0.f));
    *(float4*)(ht + (rg * 4 + i) * ST_E + tx * 4) = hv;
  }
  __syncthreads();
  float acc2[4][4];
#pragma unroll
  for (int i = 0; i < 4; i++)
#pragma unroll
    for (int j = 0; j < 4; j++) acc2[i][j] = 0.f;
#pragma unroll 4
  for (int k = 0; k < 64; k++) {
    int kk = (k + s2) & 63;
    float a0 = ht[(rg * 4 + 0) * ST_E + kk];
    float a1 = ht[(rg * 4 + 1) * ST_E + kk];
    float a2 = ht[(rg * 4 + 2) * ST_E + kk];
    float a3 = ht[(rg * 4 + 3) * ST_E + kk];
    float4 bv = *(const float4*)(w2l + kk * ST_W + tx * 4);
    acc2[0][0] = fmaf(a0, bv.x, acc2[0][0]); acc2[0][1] = fmaf(a0, bv.y, acc2[0][1]);
    acc2[0][2] = fmaf(a0, bv.z, acc2[0][2]); acc2[0][3] = fmaf(a0, bv.w, acc2[0][3]);
    acc2[1][0] = fmaf(a1, bv.x, acc2[1][0]); acc2[1][1] = fmaf(a1, bv.y, acc2[1][1]);
    acc2[1][2] = fmaf(a1, bv.z, acc2[1][2]); acc2[1][3] = fmaf(a1, bv.w, acc2[1][3]);
    acc2[2][0] = fmaf(a2, bv.x, acc2[2][0]); acc2[2][1] = fmaf(a2, bv.y, acc2[2][1]);
    acc2[2][2] = fmaf(a2, bv.z, acc2[2][2]); acc2[2][3] = fmaf(a2, bv.w, acc2[2][3]);
    acc2[3][0] = fmaf(a3, bv.x, acc2[3][0]); acc2[3][1] = fmaf(a3, bv.y, acc2[3][1]);
    acc2[3][2] = fmaf(a3, bv.z, acc2[3][2]); acc2[3][3] = fmaf(a3, bv.w, acc2[3][3]);
  }
  float4 b2v = *(const float4*)(b2 + tx * 4);
#pragma unroll
  for (int i = 0; i < 4; i++) {
    int n = n0 + rg * 4 + i;
    if (n < N) {
      float4 gv = *(const float4*)(gum + (size_t)n * 64 + tx * 4);
      float4 ev = *(const float4*)(et + (rg * 4 + i) * ST_E + tx * 4);
      float4 yv;
      yv.x = ev.x * fsig(gv.x + acc2[i][0] + b2v.x);
      yv.y = ev.y * fsig(gv.y + acc2[i][1] + b2v.y);
      yv.z = ev.z * fsig(gv.z + acc2[i][2] + b2v.z);
      yv.w = ev.w * fsig(gv.w + acc2[i][3] + b2v.w);
      st4bf(pk + (size_t)n * PK_STRIDE + 128 + tx * 8, yv);
    }
  }
}

// ------- fused 3-branch SpMM + edge-MLP + dinv + residual + out -------
#define CH 2

#define LOADCH(Abuf, Bbuf, I0)                                          \
  _Pragma("unroll")                                                     \
  for (int c = 0; c < CH; c++) {                                        \
    int i_ = (I0) + c;                                                  \
    int tof_ = __shfl(em.x, i_ & 15, 16);                               \
    if (i_ < cnt) {                                                     \
      const unsigned short* pr_ = pk + (size_t)tof_ + l * 8;            \
      Abuf[c] = *(const uint4*)(pr_);                                   \
      Bbuf[c] = *(const uint4*)(pr_ + 128);                             \
    }                                                                   \
  }

#define COMPCH(Abuf, Bbuf, I0)                                          \
  _Pragma("unroll")                                                     \
  for (int c = 0; c < CH; c++) {                                        \
    int i_ = (I0) + c;                                                  \
    float gg_ = __shfl(__int_as_float(em.y), i_ & 15, 16);              \
    float gu_ = __shfl(guv, i_ & 15, 16);                               \
    if (i_ < cnt) {                                                     \
      float4 v0_ = lo4(Abuf[c]);                                        \
      float4 v1_ = hi4(Abuf[c]);                                        \
      float4 vy_ = lo4(Bbuf[c]);                                        \
      float4 xt_ = hi4(Bbuf[c]);                                        \
      float pq_ = fmaxf(xb1.x + xt_.x, 0.f) * w2v.x                     \
                + fmaxf(xb1.y + xt_.y, 0.f) * w2v.y                     \
                + fmaxf(xb1.z + xt_.z, 0.f) * w2v.z                     \
                + fmaxf(xb1.w + xt_.w, 0.f) * w2v.w;                    \
      pq_ += __shfl_xor(pq_, 1, 16);                                    \
      pq_ += __shfl_xor(pq_, 2, 16);                                    \
      pq_ += __shfl_xor(pq_, 4, 16);                                    \
      pq_ += __shfl_xor(pq_, 8, 16);                                    \
      float w_ = fsig(gu_ + pq_ + b2s);                                 \
      wsum += w_;                                                       \
      fma4(acc0, gg_, v0_);                                             \
      fma4(acc1, w_, v1_);                                              \
      fma4(acc2, gg_, vy_);                                             \
    }                                                                   \
  }

// OUTM: 0 = no out (L=2 layer0);  1 = out = emb0 + rc + en (L=2 final, nt stores,
//       dead-state writes skipped); 2 = out = rc + en; 3 = out += en
// GSEL: gumbel source — 0: em.z, 1: em.w, 2: cgum[]
template <int FIRST, int OUTM, int GSEL>
__global__ __launch_bounds__(256) void spmm3f_k(const int* __restrict__ rp,
    const int4* __restrict__ emeta, const float* __restrict__ cgum,
    const unsigned short* __restrict__ pk, const unsigned short* __restrict__ xhb,
    const unsigned short* __restrict__ e2b_in,
    const float* __restrict__ b1, const float* __restrict__ W2,
    const float* __restrict__ b2, const float* __restrict__ emb0,
    unsigned short* __restrict__ pkn, unsigned short* __restrict__ e2b,
    float* __restrict__ out0, float* __restrict__ out1, float* __restrict__ out2,
    int N) {
  int g = threadIdx.x >> 4;
  int l = threadIdx.x & 15;
  int n = blockIdx.x * 16 + g;
  if (n >= N) return;
  int jb = rp[n], je = rp[n + 1];
  size_t o64 = (size_t)n * 64 + l * 4;
  float4 xh4 = ldbf4(xhb + o64);
  float4 b1v = *(const float4*)(b1 + l * 4);
  float4 xb1 = add4(xh4, b1v);
  float4 w2v = *(const float4*)(W2 + l * 4);
  float b2s = b2[0];
  float4 rc0, rc1, rc2;
  if (FIRST) {
    rc0 = *(const float4*)(emb0 + o64);
    rc1 = rc0; rc2 = rc0;
  } else {
    uint4 rA = *(const uint4*)(pk + (size_t)n * PK_STRIDE + l * 8);
    rc0 = lo4(rA);
    rc1 = hi4(rA);
    rc2 = ldbf4(e2b_in + o64);
  }
  float4 acc0 = f4z(), acc1 = f4z(), acc2 = f4z();
  float wsum = 0.f;
  for (int base = jb; base < je; base += 16) {
    int idx = base + l;
    bool valid = idx < je;
    int4 em = valid ? emeta[idx] : make_int4(0, 0, 0, 0);
    float guv;
    if (GSEL == 0) guv = __int_as_float(em.z);
    else if (GSEL == 1) guv = __int_as_float(em.w);
    else guv = valid ? cgum[idx] : 0.f;
    int cnt = min(16, je - base);
    uint4 A0[CH], B0[CH], A1[CH], B1[CH];
    LOADCH(A0, B0, 0)
    for (int i0 = 0; i0 < cnt; i0 += 2 * CH) {
      LOADCH(A1, B1, i0 + CH)
      COMPCH(A0, B0, i0)
      LOADCH(A0, B0, i0 + 2 * CH)
      COMPCH(A1, B1, i0 + CH)
    }
  }
  float dinv = (wsum > 0.f) ? __builtin_amdgcn_rcpf(wsum) : 0.f;
  float4 en0 = add4(acc0, rc0);
  acc1.x *= dinv; acc1.y *= dinv; acc1.z *= dinv; acc1.w *= dinv;
  float4 en1 = add4(acc1, rc1);
  float4 en2 = add4(acc2, rc2);
  if (OUTM != 1) {     // final layer: state is dead, skip writes
    uint4 wA;
    wA.x = pack2(en0.x, en0.y); wA.y = pack2(en0.z, en0.w);
    wA.z = pack2(en1.x, en1.y); wA.w = pack2(en1.z, en1.w);
    *(uint4*)(pkn + (size_t)n * PK_STRIDE + l * 8) = wA;
    st4bf(e2b + o64, en2);
  }
  if (OUTM == 1) {
    float4 base = *(const float4*)(emb0 + o64);
    stnt4(out0 + o64, add4(base, add4(rc0, en0)));
    stnt4(out1 + o64, add4(base, add4(rc1, en1)));
    stnt4(out2 + o64, add4(base, add4(rc2, en2)));
  } else if (OUTM == 2) {
    *(float4*)(out0 + o64) = add4(rc0, en0);
    *(float4*)(out1 + o64) = add4(rc1, en1);
    *(float4*)(out2 + o64) = add4(rc2, en2);
  } else if (OUTM == 3) {
    *(float4*)(out0 + o64) = add4(*(const float4*)(out0 + o64), en0);
    *(float4*)(out1 + o64) = add4(*(const float4*)(out1 + o64), en1);
    *(float4*)(out2 + o64) = add4(*(const float4*)(out2 + o64), en2);
  }
}

extern "C" void kernel_launch(void* const* d_in, const int* in_sizes, int n_in,
                              void* d_out, int out_size, void* d_ws, size_t ws_size,
                              hipStream_t stream) {
  const float* emb0        = (const float*)d_in[0];
  const int*   h_idx       = (const int*)d_in[1];
  const int*   t_idx       = (const int*)d_in[2];
  const float* G_values    = (const float*)d_in[3];
  const float* edge_gumbel = (const float*)d_in[4];
  const float* emb_gumbel  = (const float*)d_in[5];
  const float* edge_W1     = (const float*)d_in[6];
  const float* edge_b1     = (const float*)d_in[7];
  const float* edge_W2     = (const float*)d_in[8];
  const float* edge_b2     = (const float*)d_in[9];
  const float* emb_W1      = (const float*)d_in[10];
  const float* emb_b1      = (const float*)d_in[11];
  const float* emb_W2      = (const float*)d_in[12];
  const float* emb_b2      = (const float*)d_in[13];

  const int D = 64;
  const int N = in_sizes[0] / D;
  const int E = in_sizes[1];
  const int L = in_sizes[4] / E;
  const size_t ND = (size_t)N * D;

  char* p = (char*)d_ws;
  auto alloc = [&](size_t bytes) -> char* {
    char* r = p;
    p += (bytes + 255) & ~(size_t)255;
    return r;
  };
  unsigned short* xhb = (unsigned short*)alloc(ND * 2);
  unsigned short* e2b = (unsigned short*)alloc(ND * 2);
  unsigned short* pkA = (unsigned short*)alloc((size_t)N * PK_STRIDE * 2);
  unsigned short* pkB = (unsigned short*)alloc((size_t)N * PK_STRIDE * 2);
  int4*  emeta = (int4*)alloc((size_t)E * 16);
  float* cgum  = (float*)alloc((size_t)L * E * 4);
  int*   deg   = (int*)alloc((size_t)N * 4);
  int*   cur   = (int*)alloc((size_t)N * 4);
  int*   rp    = (int*)alloc(((size_t)N + 1) * 4);
  int*   sums  = (int*)alloc(1024 * 4);

  float* out = (float*)d_out;

  init_k<<<(N * 16 + 255) / 256, 256, 0, stream>>>(emb0, pkA, e2b, N);
  hipMemsetAsync(deg, 0, (size_t)N * 4, stream);
  hist_k<<<(E + 255) / 256, 256, 0, stream>>>(h_idx, deg, E);
  int nch = (N + 1023) / 1024;
  scanA_k<<<nch, 1024, 0, stream>>>(deg, rp, sums, N);
  scanB_k<<<1, 64, 0, stream>>>(sums, nch);
  scanC_k<<<(N + 256) / 256, 256, 0, stream>>>(rp, cur, sums, N, E);
  fill_k<<<(E + 255) / 256, 256, 0, stream>>>(h_idx, t_idx, G_values, edge_gumbel,
                                              cur, emeta, cgum, E, L);

  int nb64 = (N + 63) / 64;
  int nb16 = (N + 15) / 16;

  for (int i = 0; i < L; i++) {
    unsigned short* pkc = (i & 1) ? pkB : pkA;
    unsigned short* pkn = (i & 1) ? pkA : pkB;
    xht_k<<<nb64, 256, 0, stream>>>(pkc, edge_W1 + (size_t)i * 128 * 64, xhb, pkc, N);
    mlp2_k<<<nb64, 256, 0, stream>>>(e2b, emb_W1 + (size_t)i * 4096,
                                     emb_b1 + (size_t)i * 64,
                                     emb_W2 + (size_t)i * 4096,
                                     emb_b2 + (size_t)i * 64,
                                     emb_gumbel + (size_t)i * ND, pkc, N);
    const float* cg = cgum + (size_t)i * E;
    const float* eb1 = edge_b1 + (size_t)i * 64;
    const float* eW2 = edge_W2 + (size_t)i * 64;
    const float* eb2 = edge_b2 + i;
    if (L == 2) {
      if (i == 0)
        spmm3f_k<1, 0, 0><<<nb16, 256, 0, stream>>>(rp, emeta, cg, pkc, xhb, e2b,
                                                    eb1, eW2, eb2, emb0, pkn, e2b,
                                                    out, out + ND, out + 2 * ND, N);
      else
        spmm3f_k<0, 1, 1><<<nb16, 256, 0, stream>>>(rp, emeta, cg, pkc, xhb, e2b,
                                                    eb1, eW2, eb2, emb0, pkn, e2b,
                                                    out, out + ND, out + 2 * ND, N);
    } else {
      if (i == 0)
        spmm3f_k<1, 2, 2><<<nb16, 256, 0, stream>>>(rp, emeta, cg, pkc, xhb, e2b,
                                                    eb1, eW2, eb2, emb0, pkn, e2b,
                                                    out, out + ND, out + 2 * ND, N);
      else
        spmm3f_k<0, 3, 2><<<nb16, 256, 0, stream>>>(rp, emeta, cg, pkc, xhb, e2b,
                                                    eb1, eW2, eb2, emb0, pkn, e2b,
                                                    out, out + ND, out + 2 * ND, N);
    }
  }
}

// Round 9
// 346.252 us; speedup vs baseline: 2.3675x; 1.1841x over previous
//
#include <hip/hip_runtime.h>
#include <hip/hip_bf16.h>
#include <math.h>

// pk row: 256 bf16 = 512B, line-aligned.
//   elems 0..127  : E0E1 region, chunk c (0..15) = [e0[4c..4c+3] | e1[4c..4c+3]]
//   elems 128..255: Y2XT region, chunk c = [y2 quad | xt quad]
// e2 lives in a separate dense e2b[N][64] (never gathered).
#define PK_STRIDE 256
#define LDA 72   // LDS row stride (bf16 elems): 144B -> 2-way bank alias only (free)

typedef float v4f __attribute__((ext_vector_type(4)));
typedef __attribute__((ext_vector_type(8))) short s8;
typedef __attribute__((ext_vector_type(4))) float f4;

__device__ __forceinline__ float4 f4z() { return make_float4(0.f, 0.f, 0.f, 0.f); }
__device__ __forceinline__ void fma4(float4& a, float s, const float4& v) {
  a.x = fmaf(s, v.x, a.x); a.y = fmaf(s, v.y, a.y);
  a.z = fmaf(s, v.z, a.z); a.w = fmaf(s, v.w, a.w);
}
__device__ __forceinline__ float4 add4(const float4& a, const float4& b) {
  return make_float4(a.x + b.x, a.y + b.y, a.z + b.z, a.w + b.w);
}
__device__ __forceinline__ void stnt4(float* p, const float4& v) {
  v4f u; u.x = v.x; u.y = v.y; u.z = v.z; u.w = v.w;
  __builtin_nontemporal_store(u, (v4f*)p);
}
__device__ __forceinline__ float4 lo4(const uint4& u) {
  float4 f;
  f.x = __uint_as_float(u.x << 16);
  f.y = __uint_as_float(u.x & 0xffff0000u);
  f.z = __uint_as_float(u.y << 16);
  f.w = __uint_as_float(u.y & 0xffff0000u);
  return f;
}
__device__ __forceinline__ float4 hi4(const uint4& u) {
  float4 f;
  f.x = __uint_as_float(u.z << 16);
  f.y = __uint_as_float(u.z & 0xffff0000u);
  f.z = __uint_as_float(u.w << 16);
  f.w = __uint_as_float(u.w & 0xffff0000u);
  return f;
}
__device__ __forceinline__ float4 ldbf4(const unsigned short* p) {
  ushort4 u = *(const ushort4*)p;
  float4 f;
  f.x = __uint_as_float((unsigned)u.x << 16);
  f.y = __uint_as_float((unsigned)u.y << 16);
  f.z = __uint_as_float((unsigned)u.z << 16);
  f.w = __uint_as_float((unsigned)u.w << 16);
  return f;
}
__device__ __forceinline__ unsigned short f2bf(float v) {
  __hip_bfloat16 h = __float2bfloat16(v);
  return *reinterpret_cast<unsigned short*>(&h);
}
__device__ __forceinline__ unsigned pack2(float a, float b) {
  return ((unsigned)f2bf(b) << 16) | (unsigned)f2bf(a);
}
__device__ __forceinline__ void st4bf(unsigned short* p, const float4& v) {
  ushort4 u;
  u.x = f2bf(v.x); u.y = f2bf(v.y); u.z = f2bf(v.z); u.w = f2bf(v.w);
  *(ushort4*)p = u;
}
__device__ __forceinline__ float fsig(float x) {
  return __builtin_amdgcn_rcpf(1.f + __expf(-x));
}

// -------- init: pk0 E0E1 = [emb0|emb0]; e2b = emb0 --------
__global__ void init_k(const float* __restrict__ emb0, unsigned short* __restrict__ pk0,
                       unsigned short* __restrict__ e2b, int N) {
  int idx = blockIdx.x * blockDim.x + threadIdx.x;
  int n = idx >> 4, q = idx & 15;
  if (n >= N) return;
  float4 v = *(const float4*)(emb0 + (size_t)n * 64 + q * 4);
  unsigned p01 = pack2(v.x, v.y), p23 = pack2(v.z, v.w);
  uint4 u = make_uint4(p01, p23, p01, p23);
  *(uint4*)(pk0 + (size_t)n * PK_STRIDE + q * 8) = u;
  st4bf(e2b + (size_t)n * 64 + q * 4, v);
}

// ---------------- CSR build ----------------
__global__ void hist_k(const int* __restrict__ h, int* __restrict__ deg, int E) {
  int i = blockIdx.x * blockDim.x + threadIdx.x;
  if (i < E) atomicAdd(&deg[h[i]], 1);
}

__global__ void scanA_k(const int* __restrict__ deg, int* __restrict__ rp,
                        int* __restrict__ sums, int N) {
  __shared__ int s[1024];
  int i = blockIdx.x * 1024 + threadIdx.x;
  int v = (i < N) ? deg[i] : 0;
  s[threadIdx.x] = v;
  __syncthreads();
  for (int off = 1; off < 1024; off <<= 1) {
    int t = (threadIdx.x >= (unsigned)off) ? s[threadIdx.x - off] : 0;
    __syncthreads();
    s[threadIdx.x] += t;
    __syncthreads();
  }
  if (i < N) rp[i] = s[threadIdx.x] - v;
  if (threadIdx.x == 1023) sums[blockIdx.x] = s[1023];
}

__global__ void scanB_k(int* sums, int nch) {
  int lane = threadIdx.x;   // 64 threads
  int run = 0;
  for (int base = 0; base < nch; base += 64) {
    int v = (base + lane < nch) ? sums[base + lane] : 0;
    int incl = v;
    for (int off = 1; off < 64; off <<= 1) {
      int t = __shfl_up(incl, off, 64);
      if (lane >= off) incl += t;
    }
    if (base + lane < nch) sums[base + lane] = run + (incl - v);
    run += __shfl(incl, 63, 64);
  }
}

__global__ void scanC_k(int* __restrict__ rp, int* __restrict__ cur,
                        const int* __restrict__ sums, int N, int E) {
  int i = blockIdx.x * blockDim.x + threadIdx.x;
  if (i < N) {
    int v = rp[i] + sums[i >> 10];
    rp[i] = v; cur[i] = v;
  } else if (i == N) {
    rp[N] = E;
  }
}

// fill: one 16B emeta write per edge {toff, G, gum_l0, gum_l1}; cgum only if L>2
__global__ void fill_k(const int* __restrict__ h, const int* __restrict__ t_idx,
                       const float* __restrict__ G, const float* __restrict__ gum,
                       int* __restrict__ cur, int4* __restrict__ emeta,
                       float* __restrict__ cgum, int E, int L) {
  int i = blockIdx.x * blockDim.x + threadIdx.x;
  if (i < E) {
    int pos = atomicAdd(&cur[h[i]], 1);
    int4 em;
    em.x = t_idx[i] * PK_STRIDE;
    em.y = __float_as_int(G[i]);
    em.z = __float_as_int(gum[i]);
    em.w = (L > 1) ? __float_as_int(gum[(size_t)E + i]) : 0;
    emeta[pos] = em;
    if (L > 2)
      for (int l = 2; l < L; l++) cgum[(size_t)l * E + pos] = gum[(size_t)l * E + i];
  }
}

// ------- weight prep: transpose + bf16 once -------
// wxT[l][j][k]: j<64 -> edge_W1[l][k][j] (xh); j>=64 -> edge_W1[l][64+k][j-64] (xt)
// w1T[l][n][k] = emb_W1[l][k][n];  w2T[l][n][k] = emb_W2[l][k][n]
__global__ void wprep_k(const float* __restrict__ edge_W1,
                        const float* __restrict__ emb_W1,
                        const float* __restrict__ emb_W2,
                        unsigned short* __restrict__ wxT,
                        unsigned short* __restrict__ w1T,
                        unsigned short* __restrict__ w2T, int L) {
  const int per = 128 * 64 + 64 * 64 + 64 * 64;   // 16384
  int i = blockIdx.x * blockDim.x + threadIdx.x;
  if (i >= L * per) return;
  int layer = i / per, r = i % per;
  if (r < 8192) {
    int j = r >> 6, k = r & 63;
    float v = (j < 64) ? edge_W1[((size_t)layer * 128 + k) * 64 + j]
                       : edge_W1[((size_t)layer * 128 + 64 + k) * 64 + (j - 64)];
    wxT[(size_t)layer * 8192 + j * 64 + k] = f2bf(v);
  } else if (r < 8192 + 4096) {
    int q = r - 8192; int n = q >> 6, k = q & 63;
    w1T[(size_t)layer * 4096 + n * 64 + k] =
        f2bf(emb_W1[((size_t)layer * 64 + k) * 64 + n]);
  } else {
    int q = r - 12288; int n = q >> 6, k = q & 63;
    w2T[(size_t)layer * 4096 + n * 64 + k] =
        f2bf(emb_W2[((size_t)layer * 64 + k) * 64 + n]);
  }
}

// ------- fused dense layer (MFMA): xh|xt = e1@Wx ; y2 = sig(gum+mlp(e2))*e2 -------
// 64 nodes/block, 4 waves x 16 rows. mfma_f32_16x16x32_bf16:
//   A: lane holds A[l&15][8*(l>>4)+i]; B: B[8*(l>>4)+i][l&15]
//   C/D: col=l&15, row=(l>>4)*4+reg   [HW-verified mapping, learn_hip m89/m91]
__global__ __launch_bounds__(256) void dense_k(
    const unsigned short* __restrict__ pkin,   // e1 source (E0E1 hi quads)
    const unsigned short* __restrict__ e2b,
    const unsigned short* __restrict__ wxT,    // [128][64] bf16
    const unsigned short* __restrict__ w1T,    // [64][64]
    const unsigned short* __restrict__ w2T,    // [64][64]
    const float* __restrict__ b1,              // emb_b1[64]
    const float* __restrict__ b2,              // emb_b2[64]
    const float* __restrict__ gum,             // [N][64] fp32
    unsigned short* __restrict__ xhb,
    unsigned short* __restrict__ pk,           // Y2XT writes
    int N) {
  __shared__ unsigned short a1[64 * LDA];      // e1, reused as ht
  __shared__ unsigned short a2[64 * LDA];      // e2
  __shared__ unsigned short wx[128 * LDA];
  __shared__ unsigned short w1[64 * LDA];
  __shared__ unsigned short w2[64 * LDA];
  int tid = threadIdx.x;
  int n0 = blockIdx.x * 64;
  for (int i = tid; i < 64 * 16; i += 256) {
    int r = i >> 4, c = i & 15;
    ushort4 v1 = make_ushort4(0, 0, 0, 0), v2 = v1;
    if (n0 + r < N) {
      v1 = *(const ushort4*)(pkin + (size_t)(n0 + r) * PK_STRIDE + c * 8 + 4);
      v2 = *(const ushort4*)(e2b + (size_t)(n0 + r) * 64 + c * 4);
    }
    *(ushort4*)(a1 + r * LDA + c * 4) = v1;
    *(ushort4*)(a2 + r * LDA + c * 4) = v2;
  }
  for (int i = tid; i < 128 * 8; i += 256) {
    int r = i >> 3, s = i & 7;
    *(uint4*)(wx + r * LDA + s * 8) = *(const uint4*)(wxT + r * 64 + s * 8);
  }
  for (int i = tid; i < 64 * 8; i += 256) {
    int r = i >> 3, s = i & 7;
    *(uint4*)(w1 + r * LDA + s * 8) = *(const uint4*)(w1T + r * 64 + s * 8);
    *(uint4*)(w2 + r * LDA + s * 8) = *(const uint4*)(w2T + r * 64 + s * 8);
  }
  __syncthreads();
  int wv = tid >> 6, l = tid & 63;
  int l15 = l & 15, lg = l >> 4;
  int wr = wv * 16;
  int arow = wr + l15;
  // A1 frags (e1), K=64 -> 2 steps of 32
  s8 af1_0 = *(const s8*)(a1 + arow * LDA + 8 * lg);
  s8 af1_1 = *(const s8*)(a1 + arow * LDA + 32 + 8 * lg);
  // GEMM_X: ct 0..3 -> xh cols, ct 4..7 -> xt cols
#pragma unroll
  for (int ct = 0; ct < 8; ct++) {
    f4 acc = {0.f, 0.f, 0.f, 0.f};
    s8 b0 = *(const s8*)(wx + (ct * 16 + l15) * LDA + 8 * lg);
    s8 bI = *(const s8*)(wx + (ct * 16 + l15) * LDA + 32 + 8 * lg);
    acc = __builtin_amdgcn_mfma_f32_16x16x32_bf16(af1_0, b0, acc, 0, 0, 0);
    acc = __builtin_amdgcn_mfma_f32_16x16x32_bf16(af1_1, bI, acc, 0, 0, 0);
#pragma unroll
    for (int j = 0; j < 4; j++) {
      int n = n0 + wr + lg * 4 + j;
      if (n < N) {
        if (ct < 4) {
          xhb[(size_t)n * 64 + ct * 16 + l15] = f2bf(acc[j]);
        } else {
          int c2 = (ct - 4) * 16 + l15;
          pk[(size_t)n * PK_STRIDE + 128 + (c2 >> 2) * 8 + 4 + (c2 & 3)] = f2bf(acc[j]);
        }
      }
    }
  }
  // A2 frags (e2)
  s8 af2_0 = *(const s8*)(a2 + arow * LDA + 8 * lg);
  s8 af2_1 = *(const s8*)(a2 + arow * LDA + 32 + 8 * lg);
  // GEMM_1: ht = relu(e2@W1 + b1) -> write into a1 (own wave rows only)
#pragma unroll
  for (int ct = 0; ct < 4; ct++) {
    f4 acc = {0.f, 0.f, 0.f, 0.f};
    s8 b0 = *(const s8*)(w1 + (ct * 16 + l15) * LDA + 8 * lg);
    s8 bI = *(const s8*)(w1 + (ct * 16 + l15) * LDA + 32 + 8 * lg);
    acc = __builtin_amdgcn_mfma_f32_16x16x32_bf16(af2_0, b0, acc, 0, 0, 0);
    acc = __builtin_amdgcn_mfma_f32_16x16x32_bf16(af2_1, bI, acc, 0, 0, 0);
    float bb = b1[ct * 16 + l15];
#pragma unroll
    for (int j = 0; j < 4; j++) {
      float h = fmaxf(acc[j] + bb, 0.f);
      a1[(wr + lg * 4 + j) * LDA + ct * 16 + l15] = f2bf(h);
    }
  }
  // A_h frags from ht (same-wave rows; compiler orders ds write->read)
  s8 afh_0 = *(const s8*)(a1 + arow * LDA + 8 * lg);
  s8 afh_1 = *(const s8*)(a1 + arow * LDA + 32 + 8 * lg);
  // GEMM_2 + gate epilogue -> y2
#pragma unroll
  for (int ct = 0; ct < 4; ct++) {
    f4 acc = {0.f, 0.f, 0.f, 0.f};
    s8 b0 = *(const s8*)(w2 + (ct * 16 + l15) * LDA + 8 * lg);
    s8 bI = *(const s8*)(w2 + (ct * 16 + l15) * LDA + 32 + 8 * lg);
    acc = __builtin_amdgcn_mfma_f32_16x16x32_bf16(afh_0, b0, acc, 0, 0, 0);
    acc = __builtin_amdgcn_mfma_f32_16x16x32_bf16(afh_1, bI, acc, 0, 0, 0);
    int c2 = ct * 16 + l15;
    float bb = b2[c2];
#pragma unroll
    for (int j = 0; j < 4; j++) {
      int row = wr + lg * 4 + j;
      int n = n0 + row;
      if (n < N) {
        float gv = gum[(size_t)n * 64 + c2];
        float e2v = __uint_as_float((unsigned)a2[row * LDA + c2] << 16);
        float y = e2v * fsig(gv + acc[j] + bb);
        pk[(size_t)n * PK_STRIDE + 128 + (c2 >> 2) * 8 + (c2 & 3)] = f2bf(y);
      }
    }
  }
}

// ------- fused 3-branch SpMM + edge-MLP + dinv + residual + out -------
#define CH 2

#define LOADCH(Abuf, Bbuf, I0)                                          \
  _Pragma("unroll")                                                     \
  for (int c = 0; c < CH; c++) {                                        \
    int i_ = (I0) + c;                                                  \
    int tof_ = __shfl(em.x, i_ & 15, 16);                               \
    if (i_ < cnt) {                                                     \
      const unsigned short* pr_ = pk + (size_t)tof_ + l * 8;            \
      Abuf[c] = *(const uint4*)(pr_);                                   \
      Bbuf[c] = *(const uint4*)(pr_ + 128);                             \
    }                                                                   \
  }

#define COMPCH(Abuf, Bbuf, I0)                                          \
  _Pragma("unroll")                                                     \
  for (int c = 0; c < CH; c++) {                                        \
    int i_ = (I0) + c;                                                  \
    float gg_ = __shfl(__int_as_float(em.y), i_ & 15, 16);              \
    float gu_ = __shfl(guv, i_ & 15, 16);                               \
    if (i_ < cnt) {                                                     \
      float4 v0_ = lo4(Abuf[c]);                                        \
      float4 v1_ = hi4(Abuf[c]);                                        \
      float4 vy_ = lo4(Bbuf[c]);                                        \
      float4 xt_ = hi4(Bbuf[c]);                                        \
      float pq_ = fmaxf(xb1.x + xt_.x, 0.f) * w2v.x                     \
                + fmaxf(xb1.y + xt_.y, 0.f) * w2v.y                     \
                + fmaxf(xb1.z + xt_.z, 0.f) * w2v.z                     \
                + fmaxf(xb1.w + xt_.w, 0.f) * w2v.w;                    \
      pq_ += __shfl_xor(pq_, 1, 16);                                    \
      pq_ += __shfl_xor(pq_, 2, 16);                                    \
      pq_ += __shfl_xor(pq_, 4, 16);                                    \
      pq_ += __shfl_xor(pq_, 8, 16);                                    \
      float w_ = fsig(gu_ + pq_ + b2s);                                 \
      wsum += w_;                                                       \
      fma4(acc0, gg_, v0_);                                             \
      fma4(acc1, w_, v1_);                                              \
      fma4(acc2, gg_, vy_);                                             \
    }                                                                   \
  }

// OUTM: 0 = no out (L=2 layer0);  1 = out = emb0 + rc + en (L=2 final, nt stores,
//       dead-state writes skipped); 2 = out = rc + en; 3 = out += en
// GSEL: gumbel source — 0: em.z, 1: em.w, 2: cgum[]
template <int FIRST, int OUTM, int GSEL>
__global__ __launch_bounds__(256) void spmm3f_k(const int* __restrict__ rp,
    const int4* __restrict__ emeta, const float* __restrict__ cgum,
    const unsigned short* __restrict__ pk, const unsigned short* __restrict__ xhb,
    const unsigned short* __restrict__ e2b_in,
    const float* __restrict__ b1, const float* __restrict__ W2,
    const float* __restrict__ b2, const float* __restrict__ emb0,
    unsigned short* __restrict__ pkn, unsigned short* __restrict__ e2b,
    float* __restrict__ out0, float* __restrict__ out1, float* __restrict__ out2,
    int N) {
  int g = threadIdx.x >> 4;
  int l = threadIdx.x & 15;
  int n = blockIdx.x * 16 + g;
  if (n >= N) return;
  int jb = rp[n], je = rp[n + 1];
  size_t o64 = (size_t)n * 64 + l * 4;
  float4 xh4 = ldbf4(xhb + o64);
  float4 b1v = *(const float4*)(b1 + l * 4);
  float4 xb1 = add4(xh4, b1v);
  float4 w2v = *(const float4*)(W2 + l * 4);
  float b2s = b2[0];
  float4 rc0, rc1, rc2;
  if (FIRST) {
    rc0 = *(const float4*)(emb0 + o64);
    rc1 = rc0; rc2 = rc0;
  } else {
    uint4 rA = *(const uint4*)(pk + (size_t)n * PK_STRIDE + l * 8);
    rc0 = lo4(rA);
    rc1 = hi4(rA);
    rc2 = ldbf4(e2b_in + o64);
  }
  float4 acc0 = f4z(), acc1 = f4z(), acc2 = f4z();
  float wsum = 0.f;
  for (int base = jb; base < je; base += 16) {
    int idx = base + l;
    bool valid = idx < je;
    int4 em = valid ? emeta[idx] : make_int4(0, 0, 0, 0);
    float guv;
    if (GSEL == 0) guv = __int_as_float(em.z);
    else if (GSEL == 1) guv = __int_as_float(em.w);
    else guv = valid ? cgum[idx] : 0.f;
    int cnt = min(16, je - base);
    uint4 A0[CH], B0[CH], A1[CH], B1[CH];
    LOADCH(A0, B0, 0)
    for (int i0 = 0; i0 < cnt; i0 += 2 * CH) {
      LOADCH(A1, B1, i0 + CH)
      COMPCH(A0, B0, i0)
      LOADCH(A0, B0, i0 + 2 * CH)
      COMPCH(A1, B1, i0 + CH)
    }
  }
  float dinv = (wsum > 0.f) ? __builtin_amdgcn_rcpf(wsum) : 0.f;
  float4 en0 = add4(acc0, rc0);
  acc1.x *= dinv; acc1.y *= dinv; acc1.z *= dinv; acc1.w *= dinv;
  float4 en1 = add4(acc1, rc1);
  float4 en2 = add4(acc2, rc2);
  if (OUTM != 1) {     // final layer: state is dead, skip writes
    uint4 wA;
    wA.x = pack2(en0.x, en0.y); wA.y = pack2(en0.z, en0.w);
    wA.z = pack2(en1.x, en1.y); wA.w = pack2(en1.z, en1.w);
    *(uint4*)(pkn + (size_t)n * PK_STRIDE + l * 8) = wA;
    st4bf(e2b + o64, en2);
  }
  if (OUTM == 1) {
    float4 base = *(const float4*)(emb0 + o64);
    stnt4(out0 + o64, add4(base, add4(rc0, en0)));
    stnt4(out1 + o64, add4(base, add4(rc1, en1)));
    stnt4(out2 + o64, add4(base, add4(rc2, en2)));
  } else if (OUTM == 2) {
    *(float4*)(out0 + o64) = add4(rc0, en0);
    *(float4*)(out1 + o64) = add4(rc1, en1);
    *(float4*)(out2 + o64) = add4(rc2, en2);
  } else if (OUTM == 3) {
    *(float4*)(out0 + o64) = add4(*(const float4*)(out0 + o64), en0);
    *(float4*)(out1 + o64) = add4(*(const float4*)(out1 + o64), en1);
    *(float4*)(out2 + o64) = add4(*(const float4*)(out2 + o64), en2);
  }
}

extern "C" void kernel_launch(void* const* d_in, const int* in_sizes, int n_in,
                              void* d_out, int out_size, void* d_ws, size_t ws_size,
                              hipStream_t stream) {
  const float* emb0        = (const float*)d_in[0];
  const int*   h_idx       = (const int*)d_in[1];
  const int*   t_idx       = (const int*)d_in[2];
  const float* G_values    = (const float*)d_in[3];
  const float* edge_gumbel = (const float*)d_in[4];
  const float* emb_gumbel  = (const float*)d_in[5];
  const float* edge_W1     = (const float*)d_in[6];
  const float* edge_b1     = (const float*)d_in[7];
  const float* edge_W2     = (const float*)d_in[8];
  const float* edge_b2     = (const float*)d_in[9];
  const float* emb_W1      = (const float*)d_in[10];
  const float* emb_b1      = (const float*)d_in[11];
  const float* emb_W2      = (const float*)d_in[12];
  const float* emb_b2      = (const float*)d_in[13];

  const int D = 64;
  const int N = in_sizes[0] / D;
  const int E = in_sizes[1];
  const int L = in_sizes[4] / E;
  const size_t ND = (size_t)N * D;

  char* p = (char*)d_ws;
  auto alloc = [&](size_t bytes) -> char* {
    char* r = p;
    p += (bytes + 255) & ~(size_t)255;
    return r;
  };
  unsigned short* xhb = (unsigned short*)alloc(ND * 2);
  unsigned short* e2b = (unsigned short*)alloc(ND * 2);
  unsigned short* pkA = (unsigned short*)alloc((size_t)N * PK_STRIDE * 2);
  unsigned short* pkB = (unsigned short*)alloc((size_t)N * PK_STRIDE * 2);
  int4*  emeta = (int4*)alloc((size_t)E * 16);
  float* cgum  = (float*)alloc((size_t)L * E * 4);
  unsigned short* wxT = (unsigned short*)alloc((size_t)L * 8192 * 2);
  unsigned short* w1T = (unsigned short*)alloc((size_t)L * 4096 * 2);
  unsigned short* w2T = (unsigned short*)alloc((size_t)L * 4096 * 2);
  int*   deg   = (int*)alloc((size_t)N * 4);
  int*   cur   = (int*)alloc((size_t)N * 4);
  int*   rp    = (int*)alloc(((size_t)N + 1) * 4);
  int*   sums  = (int*)alloc(1024 * 4);

  float* out = (float*)d_out;

  init_k<<<(N * 16 + 255) / 256, 256, 0, stream>>>(emb0, pkA, e2b, N);
  hipMemsetAsync(deg, 0, (size_t)N * 4, stream);
  hist_k<<<(E + 255) / 256, 256, 0, stream>>>(h_idx, deg, E);
  int nch = (N + 1023) / 1024;
  scanA_k<<<nch, 1024, 0, stream>>>(deg, rp, sums, N);
  scanB_k<<<1, 64, 0, stream>>>(sums, nch);
  scanC_k<<<(N + 256) / 256, 256, 0, stream>>>(rp, cur, sums, N, E);
  fill_k<<<(E + 255) / 256, 256, 0, stream>>>(h_idx, t_idx, G_values, edge_gumbel,
                                              cur, emeta, cgum, E, L);
  wprep_k<<<(L * 16384 + 255) / 256, 256, 0, stream>>>(edge_W1, emb_W1, emb_W2,
                                                       wxT, w1T, w2T, L);

  int nb64 = (N + 63) / 64;
  int nb16 = (N + 15) / 16;

  for (int i = 0; i < L; i++) {
    unsigned short* pkc = (i & 1) ? pkB : pkA;
    unsigned short* pkn = (i & 1) ? pkA : pkB;
    dense_k<<<nb64, 256, 0, stream>>>(pkc, e2b,
                                      wxT + (size_t)i * 8192,
                                      w1T + (size_t)i * 4096,
                                      w2T + (size_t)i * 4096,
                                      emb_b1 + (size_t)i * 64,
                                      emb_b2 + (size_t)i * 64,
                                      emb_gumbel + (size_t)i * ND,
                                      xhb, pkc, N);
    const float* cg = cgum + (size_t)i * E;
    const float* eb1 = edge_b1 + (size_t)i * 64;
    const float* eW2 = edge_W2 + (size_t)i * 64;
    const float* eb2 = edge_b2 + i;
    if (L == 2) {
      if (i == 0)
        spmm3f_k<1, 0, 0><<<nb16, 256, 0, stream>>>(rp, emeta, cg, pkc, xhb, e2b,
                                                    eb1, eW2, eb2, emb0, pkn, e2b,
                                                    out, out + ND, out + 2 * ND, N);
      else
        spmm3f_k<0, 1, 1><<<nb16, 256, 0, stream>>>(rp, emeta, cg, pkc, xhb, e2b,
                                                    eb1, eW2, eb2, emb0, pkn, e2b,
                                                    out, out + ND, out + 2 * ND, N);
    } else {
      if (i == 0)
        spmm3f_k<1, 2, 2><<<nb16, 256, 0, stream>>>(rp, emeta, cg, pkc, xhb, e2b,
                                                    eb1, eW2, eb2, emb0, pkn, e2b,
                                                    out, out + ND, out + 2 * ND, N);
      else
        spmm3f_k<0, 3, 2><<<nb16, 256, 0, stream>>>(rp, emeta, cg, pkc, xhb, e2b,
                                                    eb1, eW2, eb2, emb0, pkn, e2b,
                                                    out, out + ND, out + 2 * ND, N);
    }
  }
}